// Round 6
// baseline (1630.659 us; speedup 1.0000x reference)
//
#include <hip/hip_runtime.h>
#include <math.h>

#define NBATCH 8
#define NPTS   2048
#define NPOINT 512
#define KNB    16
#define NROWS  (NBATCH*NPOINT*KNB)   // 65536

// ---------------------------------------------------------------------------
// Scratch in static __device__ globals (zero-init, allocated at module load).
// RULE: referenced ONLY inside device code (host use passes the host shadow
// address -> GPU fault; that was the r1-r4 crash). Fully rewritten each call.
// ---------------------------------------------------------------------------
__device__ __align__(16) int   g_fidx[NBATCH * NPOINT];           //  16 KB
__device__ __align__(16) int   g_knn [NROWS];                     // 256 KB
__device__ __align__(16) float g_sums[1024];                      //   4 KB
__device__ __align__(16) float g_pT  [NBATCH * NPTS * 64];        //   4 MB
__device__ __align__(16) float g_S   [(size_t)NROWS * 8];         //   2 MB
__device__ __align__(16) float g_act1[(size_t)NROWS * 64];        //  16 MB
__device__ __align__(16) float g_act2[(size_t)NROWS * 128];       //  32 MB

// Zero the BN-stats scratch (1024 floats) — must run every call (atomics).
__global__ void zero_kernel() {
    g_sums[blockIdx.x * 256 + threadIdx.x] = 0.0f;
}

// ---------------------------------------------------------------------------
// FPS: one wave per batch. Coords + running dists in registers (32 pts/lane).
// Matches numpy: contract(off), direct (x-c)^2 form, first-index argmax.
// ---------------------------------------------------------------------------
__global__ __launch_bounds__(64, 1) void fps_kernel(const float* __restrict__ xyz) {
    #pragma clang fp contract(off)
    const int b = blockIdx.x;
    const int lane = threadIdx.x;
    const float* xb = xyz + b * 3 * NPTS;
    float x[32], y[32], z[32], d[32];
    #pragma unroll
    for (int j = 0; j < 32; ++j) {
        int p = j * 64 + lane;
        x[j] = xb[p];
        y[j] = xb[NPTS + p];
        z[j] = xb[2*NPTS + p];
        d[j] = 1e10f;
    }
    int far = 0;
    for (int i = 0; i < NPOINT; ++i) {
        if (lane == 0) g_fidx[b * NPOINT + i] = far;
        float cx = xb[far];
        float cy = xb[NPTS + far];
        float cz = xb[2*NPTS + far];
        float best = -1.0f; int bi = 0;
        #pragma unroll
        for (int j = 0; j < 32; ++j) {
            float dx = x[j] - cx;
            float dy = y[j] - cy;
            float dz = z[j] - cz;
            float dd = dx*dx + dy*dy;   // ((dx^2+dy^2)+dz^2) like np.sum axis=-1
            dd = dd + dz*dz;
            float dn = fminf(d[j], dd);
            d[j] = dn;
            if (dn > best) { best = dn; bi = j * 64 + lane; }  // strict > : first max
        }
        #pragma unroll
        for (int m = 32; m >= 1; m >>= 1) {
            float ov = __shfl_xor(best, m);
            int   oi = __shfl_xor(bi, m);
            if (ov > best || (ov == best && oi < bi)) { best = ov; bi = oi; }
        }
        far = bi & (NPTS - 1);
    }
}

// ---------------------------------------------------------------------------
// KNN: one wave per query. Expanded |a|^2+|b|^2-2ab form (contract off) to
// match np tie behavior; 16 rounds of wave-min with index tie-break.
// ---------------------------------------------------------------------------
__global__ __launch_bounds__(256) void knn_kernel(const float* __restrict__ xyz) {
    #pragma clang fp contract(off)
    const int wave = blockIdx.x * 4 + (threadIdx.x >> 6);   // = b*512 + p
    const int lane = threadIdx.x & 63;
    const int b = wave >> 9;
    const float* xb = xyz + b * 3 * NPTS;
    const int fi = g_fidx[wave] & (NPTS - 1);
    float ax = xb[fi];
    float ay = xb[NPTS + fi];
    float az = xb[2*NPTS + fi];
    float sa = ax*ax + ay*ay; sa = sa + az*az;
    float d[32];
    #pragma unroll
    for (int j = 0; j < 32; ++j) {
        int p = j * 64 + lane;
        float bx = xb[p];
        float by = xb[NPTS + p];
        float bz = xb[2*NPTS + p];
        float sb = bx*bx + by*by; sb = sb + bz*bz;
        float dot = ax*bx + ay*by; dot = dot + az*bz;
        float t1 = sa + sb;
        float t2 = 2.0f * dot;
        d[j] = t1 - t2;
    }
    for (int r = 0; r < KNB; ++r) {
        float best = 1e30f; int bi = 0x7fffffff;
        #pragma unroll
        for (int j = 0; j < 32; ++j) {
            if (d[j] < best) { best = d[j]; bi = j * 64 + lane; }
        }
        #pragma unroll
        for (int m = 32; m >= 1; m >>= 1) {
            float ov = __shfl_xor(best, m);
            int   oi = __shfl_xor(bi, m);
            if (ov < best || (ov == best && oi < bi)) { best = ov; bi = oi; }
        }
        bi &= (NPTS - 1);
        if (lane == 0) g_knn[wave * KNB + r] = bi;
        int rl = bi & 63, rs = bi >> 6;
        if (lane == rl) {
            #pragma unroll
            for (int j = 0; j < 32; ++j) if (j == rs) d[j] = 1e30f;
        }
    }
}

// ---------------------------------------------------------------------------
// Transpose points [b][c][n] -> [b][n][c] (f32) for coalesced gather.
// ---------------------------------------------------------------------------
__global__ __launch_bounds__(256) void transpose_kernel(const float* __restrict__ points) {
    __shared__ float tile[64][65];
    const int blk = blockIdx.x;            // 8 batches * 32 n-chunks
    const int b = blk >> 5;
    const int n0 = (blk & 31) * 64;
    const int t = threadIdx.x;
    const int lane = t & 63, q = t >> 6;
    #pragma unroll
    for (int i = 0; i < 16; ++i) {
        int c = q * 16 + i;
        tile[c][lane] = points[(b * 64 + c) * NPTS + n0 + lane];
    }
    __syncthreads();
    #pragma unroll
    for (int i = 0; i < 16; ++i) {
        int n = q * 16 + i;
        g_pT[(size_t)(b * NPTS + n0 + n) * 64 + lane] = tile[lane][n];
    }
}

// ---------------------------------------------------------------------------
// Geometry + ONE layer's scoring MLP (h=relu(W1 g+b1), s=softmax(W2 h+b2)).
// One thread per (b,p,k); dist min/max over k via width-16 shuffles.
// ---------------------------------------------------------------------------
__global__ __launch_bounds__(256) void score_kernel(
    const float* __restrict__ xyz, const float* __restrict__ nrm,
    const float* __restrict__ Xa, const float* __restrict__ Ya,
    const float* __restrict__ w1, const float* __restrict__ b1,
    const float* __restrict__ w2, const float* __restrict__ b2) {
    __shared__ float w1s[16][10];
    __shared__ float b1s[16];
    __shared__ float w2s[8][16];
    __shared__ float b2s[8];
    const int t = threadIdx.x;
    if (t < 160) w1s[t / 10][t % 10] = w1[t];
    if (t < 16)  b1s[t] = b1[t];
    if (t < 128) w2s[t / 16][t % 16] = w2[t];
    if (t < 8)   b2s[t] = b2[t];
    __syncthreads();
    const int row = blockIdx.x * 256 + t;
    const int b = row >> 13;
    const int p = (row >> 4) & 511;
    const int n = g_knn[row] & (NPTS - 1);
    const int fi = g_fidx[b * NPOINT + p] & (NPTS - 1);
    const float* xb = xyz + b * 3 * NPTS;
    const float* nb = nrm + b * 3 * NPTS;
    const float* Xb = Xa  + b * 3 * NPTS;
    const float* Yb = Ya  + b * 3 * NPTS;
    float gx, gy, gz, sq, draw, nnv;
    {
        #pragma clang fp contract(off)
        gx = xb[n]        - xb[fi];
        gy = xb[NPTS + n] - xb[NPTS + fi];
        gz = xb[2*NPTS+n] - xb[2*NPTS+fi];
        sq = gx*gx + gy*gy;
        sq = sq + gz*gz;
        draw = sqrtf(sq + 1e-10f);
        nnv = sqrtf(sq);
    }
    float dmin = draw, dmax = draw;
    #pragma unroll
    for (int m = 1; m < 16; m <<= 1) {
        dmin = fminf(dmin, __shfl_xor(dmin, m, 16));
        dmax = fmaxf(dmax, __shfl_xor(dmax, m, 16));
    }
    float dist;
    {
        #pragma clang fp contract(off)
        dist = (draw - dmin) / ((dmax - dmin) + 1e-10f);
    }
    float nx = nb[n], ny = nb[NPTS+n], nz = nb[2*NPTS+n];
    float Xx = Xb[n], Xy = Xb[NPTS+n], Xz = Xb[2*NPTS+n];
    float Yx = Yb[n], Yy = Yb[NPTS+n], Yz = Yb[2*NPTS+n];
    float g[10];
    g[0]=gx; g[1]=gy; g[2]=gz; g[3]=dist; g[4]=nx; g[5]=ny; g[6]=nz;
    {
        float vs[3][3] = {{nx,ny,nz},{Xx,Xy,Xz},{Yx,Yy,Yz}};
        #pragma unroll
        for (int a = 0; a < 3; ++a) {
            float vx=vs[a][0], vy=vs[a][1], vz=vs[a][2];
            float dot, nv;
            {
                #pragma clang fp contract(off)
                dot = gx*vx + gy*vy; dot = dot + gz*vz;
                float s2 = vx*vx + vy*vy; s2 = s2 + vz*vz;
                nv = sqrtf(s2);
            }
            float cc = dot / (nnv * nv + 1e-8f);
            cc = fminf(1.0f, fmaxf(-1.0f, cc));
            g[7+a] = acosf(cc) / 3.14159274101257324f;
        }
    }
    float h[16];
    #pragma unroll
    for (int i = 0; i < 16; ++i) {
        float a = b1s[i];
        #pragma unroll
        for (int j = 0; j < 10; ++j) a += w1s[i][j] * g[j];
        h[i] = fmaxf(a, 0.0f);
    }
    float e[8]; float mx = -1e30f;
    #pragma unroll
    for (int m = 0; m < 8; ++m) {
        float a = b2s[m];
        #pragma unroll
        for (int j = 0; j < 16; ++j) a += w2s[m][j] * h[j];
        e[m] = a; mx = fmaxf(mx, a);
    }
    float sum = 0.0f;
    #pragma unroll
    for (int m = 0; m < 8; ++m) { e[m] = expf(e[m] - mx); sum += e[m]; }
    #pragma unroll
    for (int m = 0; m < 8; ++m) g_S[(size_t)row * 8 + m] = e[m] / sum;
}

// ---------------------------------------------------------------------------
// PAConv GEMM: O[row,o] = sum_{m,c} (S[row,m]*A[row,c]) * bank[(m,c),o].
// 64x64 tile, Kc=32. A built on the fly in LDS. LDS = 16.9 KB.
// LAYER 0: A = g_pT via knn gather -> g_act1.
// LAYER 1: A = g_act1 -> g_act2.
// LAYER 2: A = g_act2 -> fused max-over-k + transpose into d_out (arg).
// Scratch buffers resolved in DEVICE code (constexpr on LAYER).
// ---------------------------------------------------------------------------
template<int LAYER, int CIN, int COUT>
__global__ __launch_bounds__(256) void gemm_kernel(const float* __restrict__ bank,
                                                   float* __restrict__ dout) {
    const float* __restrict__ A = (LAYER == 0) ? g_pT : (LAYER == 1) ? g_act1 : g_act2;
    float* __restrict__ O = (LAYER == 0) ? g_act1 : (LAYER == 1) ? g_act2 : dout;
    constexpr bool GATHER  = (LAYER == 0);
    constexpr bool FUSEMAX = (LAYER == 2);

    __shared__ float As[32][68];   // [kk][r], padded
    __shared__ float Bs[32][64];   // [kk][o]
    const int t = threadIdx.x;
    const int tx = t & 15, ty = t >> 4;
    const int row0 = blockIdx.x * 64;
    const int o0 = blockIdx.y * 64;
    const int ar = t >> 2, akk = (t & 3) * 8;   // A staging: 1 row, 8 k's
    const int bo = t & 63, bkk = t >> 6;        // B staging
    float acc[4][4] = {};
    const int KDIM = 8 * CIN;

    size_t arow;
    if (GATHER) {
        const int row = row0 + ar;
        const int b = row >> 13;
        const int n = g_knn[row] & (NPTS - 1);
        arow = (size_t)(b * NPTS + n) * 64;
    } else {
        arow = (size_t)(row0 + ar) * CIN;
    }
    const float* Srow = g_S + (size_t)(row0 + ar) * 8;

    for (int k0 = 0; k0 < KDIM; k0 += 32) {
        const int m = k0 / CIN;
        const int c0 = k0 % CIN;
        float sv = Srow[m];
        const float4* fp = reinterpret_cast<const float4*>(A + arow + c0 + akk);
        float4 fa = fp[0], fb = fp[1];
        As[akk+0][ar] = sv * fa.x; As[akk+1][ar] = sv * fa.y;
        As[akk+2][ar] = sv * fa.z; As[akk+3][ar] = sv * fa.w;
        As[akk+4][ar] = sv * fb.x; As[akk+5][ar] = sv * fb.y;
        As[akk+6][ar] = sv * fb.z; As[akk+7][ar] = sv * fb.w;
        #pragma unroll
        for (int j = 0; j < 8; ++j) {
            int kk = bkk + j * 4;
            Bs[kk][bo] = bank[(size_t)(k0 + kk) * COUT + o0 + bo];
        }
        __syncthreads();
        #pragma unroll
        for (int kk = 0; kk < 32; ++kk) {
            float a0 = As[kk][ty*4+0], a1 = As[kk][ty*4+1], a2 = As[kk][ty*4+2], a3 = As[kk][ty*4+3];
            float q0 = Bs[kk][tx*4+0], q1 = Bs[kk][tx*4+1], q2 = Bs[kk][tx*4+2], q3 = Bs[kk][tx*4+3];
            acc[0][0] += a0*q0; acc[0][1] += a0*q1; acc[0][2] += a0*q2; acc[0][3] += a0*q3;
            acc[1][0] += a1*q0; acc[1][1] += a1*q1; acc[1][2] += a1*q2; acc[1][3] += a1*q3;
            acc[2][0] += a2*q0; acc[2][1] += a2*q1; acc[2][2] += a2*q2; acc[2][3] += a2*q3;
            acc[3][0] += a3*q0; acc[3][1] += a3*q1; acc[3][2] += a3*q2; acc[3][3] += a3*q3;
        }
        __syncthreads();
    }

    if (FUSEMAX) {
        // Wave w (= t>>6) holds rows [16w, 16w+16) = all K=16 neighbors of one
        // (b,p). Reduce max over i (4 rows/thread) then lanes ^16, ^32.
        float mj[4];
        #pragma unroll
        for (int j = 0; j < 4; ++j) {
            mj[j] = fmaxf(fmaxf(acc[0][j], acc[1][j]), fmaxf(acc[2][j], acc[3][j]));
            mj[j] = fmaxf(mj[j], __shfl_xor(mj[j], 16));
            mj[j] = fmaxf(mj[j], __shfl_xor(mj[j], 32));
        }
        const int lane = t & 63, w = t >> 6;
        if (lane < 16) {
            const int bp = (row0 >> 4) + w;           // b*512 + p
            const int b = bp >> 9, p = bp & 511;
            #pragma unroll
            for (int j = 0; j < 4; ++j)
                O[(size_t)(b * 256 + o0 + lane * 4 + j) * NPOINT + p] = mj[j];
        }
    } else {
        #pragma unroll
        for (int i = 0; i < 4; ++i) {
            float4 v; v.x = acc[i][0]; v.y = acc[i][1]; v.z = acc[i][2]; v.w = acc[i][3];
            *reinterpret_cast<float4*>(O + (size_t)(row0 + ty*4 + i) * COUT + o0 + tx*4) = v;
        }
    }
}

// Per-channel sum / sumsq over 65536 rows (f32 atomics out).
// COUT=64 -> g_act1 / g_sums[0..128); COUT=128 -> g_act2 / g_sums[256..512).
template<int COUT>
__global__ __launch_bounds__(256) void bn_reduce_kernel() {
    const float* __restrict__ O = (COUT == 64) ? g_act1 : g_act2;
    float* sums = (COUT == 64) ? g_sums : (g_sums + 256);
    const int t = threadIdx.x;
    const int c = t % COUT;
    const int rs = t / COUT;
    const int RL = 256 / COUT;
    const int row0 = blockIdx.x * 256;
    float s = 0.0f, ss = 0.0f;
    for (int r = rs; r < 256; r += RL) {
        float x = O[(size_t)(row0 + r) * COUT + c];
        s += x; ss += x * x;
    }
    __shared__ float ls[256], lss[256];
    ls[t] = s; lss[t] = ss;
    __syncthreads();
    if (t < COUT) {
        for (int i = 1; i < RL; ++i) { s += ls[t + i*COUT]; ss += lss[t + i*COUT]; }
        atomicAdd(&sums[c], s);
        atomicAdd(&sums[COUT + c], ss);
    }
}

// In-place BN + relu (buffers resolved device-side).
template<int COUT>
__global__ __launch_bounds__(256) void bn_apply_kernel(const float* __restrict__ gamma,
                                                       const float* __restrict__ beta) {
    float* O = (COUT == 64) ? g_act1 : g_act2;
    const float* sums = (COUT == 64) ? g_sums : (g_sums + 256);
    const size_t e = (size_t)blockIdx.x * 256 + threadIdx.x;
    const int c = (int)(e % COUT);
    const float inv_n = 1.0f / 65536.0f;
    float mu = sums[c] * inv_n;
    float var = sums[COUT + c] * inv_n - mu * mu;
    var = fmaxf(var, 0.0f);
    float x = O[e];
    float y = (x - mu) / sqrtf(var + 1e-5f) * gamma[c] + beta[c];
    O[e] = fmaxf(y, 0.0f);
}

// Small gathered outputs: new_xyz (fidx), new_norm/new_X/new_Y (knn[...,0]).
__global__ __launch_bounds__(256) void small_out_kernel(const float* __restrict__ xyz,
                                                        const float* __restrict__ nrm,
                                                        const float* __restrict__ Xa,
                                                        const float* __restrict__ Ya,
                                                        float* __restrict__ out) {
    const int t = blockIdx.x * 256 + threadIdx.x;   // 4096 = b*512+p
    const int b = t / NPOINT, p = t % NPOINT;
    const int fi = g_fidx[t] & (NPTS - 1);
    const int n0 = g_knn[t * KNB] & (NPTS - 1);
    #pragma unroll
    for (int a = 0; a < 3; ++a) {
        out[            (b*3 + a) * NPOINT + p] = xyz[(b*3 + a) * NPTS + fi];
        out[12288 +     (b*3 + a) * NPOINT + p] = nrm[(b*3 + a) * NPTS + n0];
        out[24576 +     (b*3 + a) * NPOINT + p] = Xa [(b*3 + a) * NPTS + n0];
        out[36864 +     (b*3 + a) * NPOINT + p] = Ya [(b*3 + a) * NPTS + n0];
    }
}

// ---------------------------------------------------------------------------
extern "C" void kernel_launch(void* const* d_in, const int* in_sizes, int n_in,
                              void* d_out, int out_size, void* d_ws, size_t ws_size,
                              hipStream_t stream) {
    const float* xyz    = (const float*)d_in[0];
    const float* nrm    = (const float*)d_in[1];
    const float* Xa     = (const float*)d_in[2];
    const float* Ya     = (const float*)d_in[3];
    const float* points = (const float*)d_in[4];
    const float* w1_0 = (const float*)d_in[5];  const float* b1_0 = (const float*)d_in[6];
    const float* w2_0 = (const float*)d_in[7];  const float* b2_0 = (const float*)d_in[8];
    const float* bank0 = (const float*)d_in[9];
    const float* g0 = (const float*)d_in[10];   const float* be0 = (const float*)d_in[11];
    const float* w1_1 = (const float*)d_in[12]; const float* b1_1 = (const float*)d_in[13];
    const float* w2_1 = (const float*)d_in[14]; const float* b2_1 = (const float*)d_in[15];
    const float* bank1 = (const float*)d_in[16];
    const float* g1 = (const float*)d_in[17];   const float* be1 = (const float*)d_in[18];
    const float* w1_2 = (const float*)d_in[19]; const float* b1_2 = (const float*)d_in[20];
    const float* w2_2 = (const float*)d_in[21]; const float* b2_2 = (const float*)d_in[22];
    const float* bank2 = (const float*)d_in[23];
    float* out = (float*)d_out;
    (void)d_ws; (void)ws_size; (void)in_sizes; (void)n_in; (void)out_size;

    zero_kernel<<<4, 256, 0, stream>>>();
    fps_kernel<<<NBATCH, 64, 0, stream>>>(xyz);
    knn_kernel<<<1024, 256, 0, stream>>>(xyz);
    transpose_kernel<<<256, 256, 0, stream>>>(points);
    small_out_kernel<<<16, 256, 0, stream>>>(xyz, nrm, Xa, Ya, out);

    // layer 0: cin=64 -> cout=64 (fused gather from g_pT)
    score_kernel<<<256, 256, 0, stream>>>(xyz, nrm, Xa, Ya, w1_0, b1_0, w2_0, b2_0);
    gemm_kernel<0, 64, 64><<<dim3(1024, 1), 256, 0, stream>>>(bank0, out);
    bn_reduce_kernel<64><<<256, 256, 0, stream>>>();
    bn_apply_kernel<64><<<16384, 256, 0, stream>>>(g0, be0);

    // layer 1: cin=64 -> cout=128
    score_kernel<<<256, 256, 0, stream>>>(xyz, nrm, Xa, Ya, w1_1, b1_1, w2_1, b2_1);
    gemm_kernel<1, 64, 128><<<dim3(1024, 2), 256, 0, stream>>>(bank1, out);
    bn_reduce_kernel<128><<<256, 256, 0, stream>>>();
    bn_apply_kernel<128><<<32768, 256, 0, stream>>>(g1, be1);

    // layer 2: cin=128 -> cout=256, fused max-over-k + transpose to d_out
    score_kernel<<<256, 256, 0, stream>>>(xyz, nrm, Xa, Ya, w1_2, b1_2, w2_2, b2_2);
    gemm_kernel<2, 128, 256><<<dim3(1024, 4), 256, 0, stream>>>(bank2, out + 49152);
}

// Round 7
// 1322.965 us; speedup vs baseline: 1.2326x; 1.2326x over previous
//
#include <hip/hip_runtime.h>
#include <math.h>

#define NBATCH 8
#define NPTS   2048
#define NPOINT 512
#define KNB    16
#define NROWS  (NBATCH*NPOINT*KNB)   // 65536

// ---------------------------------------------------------------------------
// Scratch in static __device__ globals (zero-init, allocated at module load).
// RULE: referenced ONLY inside device code (host use passes the host shadow
// address -> GPU fault; that was the r1-r4 crash). Fully rewritten each call.
// ---------------------------------------------------------------------------
__device__ __align__(16) int   g_fidx[NBATCH * NPOINT];           //  16 KB
__device__ __align__(16) int   g_knn [NROWS];                     // 256 KB
__device__ __align__(16) float g_sums[1024];                      //   4 KB
__device__ __align__(16) float g_pT  [NBATCH * NPTS * 64];        //   4 MB
__device__ __align__(16) float g_S   [(size_t)NROWS * 8];         //   2 MB
__device__ __align__(16) float g_act1[(size_t)NROWS * 64];        //  16 MB
__device__ __align__(16) float g_act2[(size_t)NROWS * 128];       //  32 MB

// Zero the BN-stats scratch (1024 floats) — must run every call (atomics).
__global__ void zero_kernel() {
    g_sums[blockIdx.x * 256 + threadIdx.x] = 0.0f;
}

// ---------------------------------------------------------------------------
// FPS: one 256-thread block (4 waves) per batch; 8 points per lane in
// registers; coords mirrored in LDS so the centroid read is an LDS broadcast
// (not 3 dependent global loads). Argmax via packed u64 key
// (f32bits(dist) << 32) | ~idx : distances >= 0 so f32 bits are monotonic
// as uint, and on value ties larger ~idx == smaller idx == numpy argmax.
// Distance formula & update order identical to numpy (contract off).
// ---------------------------------------------------------------------------
__global__ __launch_bounds__(256, 1) void fps_kernel(const float* __restrict__ xyz) {
    #pragma clang fp contract(off)
    const int b = blockIdx.x;
    const int t = threadIdx.x;
    const int lane = t & 63, w = t >> 6;
    const float* xb = xyz + b * 3 * NPTS;
    __shared__ float s_x[NPTS], s_y[NPTS], s_z[NPTS];
    __shared__ unsigned long long s_key[4];
    float x[8], y[8], z[8], d[8];
    #pragma unroll
    for (int j = 0; j < 8; ++j) {
        int p = j * 256 + t;
        float vx = xb[p], vy = xb[NPTS + p], vz = xb[2*NPTS + p];
        x[j] = vx; y[j] = vy; z[j] = vz;
        s_x[p] = vx; s_y[p] = vy; s_z[p] = vz;
        d[j] = 1e10f;
    }
    __syncthreads();
    int far = 0;
    for (int i = 0; i < NPOINT; ++i) {
        if (t == 0) g_fidx[b * NPOINT + i] = far;
        float cx = s_x[far], cy = s_y[far], cz = s_z[far];
        float best = -1.0f; int bi = 0;
        #pragma unroll
        for (int j = 0; j < 8; ++j) {
            float dx = x[j] - cx;
            float dy = y[j] - cy;
            float dz = z[j] - cz;
            float dd = dx*dx + dy*dy;   // ((dx^2+dy^2)+dz^2) like np.sum axis=-1
            dd = dd + dz*dz;
            float dn = fminf(d[j], dd);
            d[j] = dn;
            if (dn > best) { best = dn; bi = j * 256 + t; }  // strict > : first idx
        }
        unsigned long long key =
            (((unsigned long long)__float_as_uint(best)) << 32) | (unsigned)(~bi);
        #pragma unroll
        for (int m = 1; m < 64; m <<= 1) {
            unsigned long long ok = __shfl_xor(key, m);
            if (ok > key) key = ok;
        }
        if (lane == 0) s_key[w] = key;
        __syncthreads();
        unsigned long long k0 = s_key[0], k1 = s_key[1];
        unsigned long long k2 = s_key[2], k3 = s_key[3];
        if (k1 > k0) k0 = k1;
        if (k3 > k2) k2 = k3;
        if (k2 > k0) k0 = k2;
        far = (int)(~(unsigned)k0) & (NPTS - 1);
        __syncthreads();   // protect s_key from next iteration's writes
    }
}

// ---------------------------------------------------------------------------
// KNN: one wave per query. Expanded |a|^2+|b|^2-2ab form (contract off) to
// match np tie behavior; 16 rounds of wave-min with index tie-break.
// ---------------------------------------------------------------------------
__global__ __launch_bounds__(256) void knn_kernel(const float* __restrict__ xyz) {
    #pragma clang fp contract(off)
    const int wave = blockIdx.x * 4 + (threadIdx.x >> 6);   // = b*512 + p
    const int lane = threadIdx.x & 63;
    const int b = wave >> 9;
    const float* xb = xyz + b * 3 * NPTS;
    const int fi = g_fidx[wave] & (NPTS - 1);
    float ax = xb[fi];
    float ay = xb[NPTS + fi];
    float az = xb[2*NPTS + fi];
    float sa = ax*ax + ay*ay; sa = sa + az*az;
    float d[32];
    #pragma unroll
    for (int j = 0; j < 32; ++j) {
        int p = j * 64 + lane;
        float bx = xb[p];
        float by = xb[NPTS + p];
        float bz = xb[2*NPTS + p];
        float sb = bx*bx + by*by; sb = sb + bz*bz;
        float dot = ax*bx + ay*by; dot = dot + az*bz;
        float t1 = sa + sb;
        float t2 = 2.0f * dot;
        d[j] = t1 - t2;
    }
    for (int r = 0; r < KNB; ++r) {
        float best = 1e30f; int bi = 0x7fffffff;
        #pragma unroll
        for (int j = 0; j < 32; ++j) {
            if (d[j] < best) { best = d[j]; bi = j * 64 + lane; }
        }
        #pragma unroll
        for (int m = 32; m >= 1; m >>= 1) {
            float ov = __shfl_xor(best, m);
            int   oi = __shfl_xor(bi, m);
            if (ov < best || (ov == best && oi < bi)) { best = ov; bi = oi; }
        }
        bi &= (NPTS - 1);
        if (lane == 0) g_knn[wave * KNB + r] = bi;
        int rl = bi & 63, rs = bi >> 6;
        if (lane == rl) {
            #pragma unroll
            for (int j = 0; j < 32; ++j) if (j == rs) d[j] = 1e30f;
        }
    }
}

// ---------------------------------------------------------------------------
// Transpose points [b][c][n] -> [b][n][c] (f32) for coalesced gather.
// ---------------------------------------------------------------------------
__global__ __launch_bounds__(256) void transpose_kernel(const float* __restrict__ points) {
    __shared__ float tile[64][65];
    const int blk = blockIdx.x;            // 8 batches * 32 n-chunks
    const int b = blk >> 5;
    const int n0 = (blk & 31) * 64;
    const int t = threadIdx.x;
    const int lane = t & 63, q = t >> 6;
    #pragma unroll
    for (int i = 0; i < 16; ++i) {
        int c = q * 16 + i;
        tile[c][lane] = points[(b * 64 + c) * NPTS + n0 + lane];
    }
    __syncthreads();
    #pragma unroll
    for (int i = 0; i < 16; ++i) {
        int n = q * 16 + i;
        g_pT[(size_t)(b * NPTS + n0 + n) * 64 + lane] = tile[lane][n];
    }
}

// ---------------------------------------------------------------------------
// Geometry + ONE layer's scoring MLP (h=relu(W1 g+b1), s=softmax(W2 h+b2)).
// One thread per (b,p,k); dist min/max over k via width-16 shuffles.
// ---------------------------------------------------------------------------
__global__ __launch_bounds__(256) void score_kernel(
    const float* __restrict__ xyz, const float* __restrict__ nrm,
    const float* __restrict__ Xa, const float* __restrict__ Ya,
    const float* __restrict__ w1, const float* __restrict__ b1,
    const float* __restrict__ w2, const float* __restrict__ b2) {
    __shared__ float w1s[16][10];
    __shared__ float b1s[16];
    __shared__ float w2s[8][16];
    __shared__ float b2s[8];
    const int t = threadIdx.x;
    if (t < 160) w1s[t / 10][t % 10] = w1[t];
    if (t < 16)  b1s[t] = b1[t];
    if (t < 128) w2s[t / 16][t % 16] = w2[t];
    if (t < 8)   b2s[t] = b2[t];
    __syncthreads();
    const int row = blockIdx.x * 256 + t;
    const int b = row >> 13;
    const int p = (row >> 4) & 511;
    const int n = g_knn[row] & (NPTS - 1);
    const int fi = g_fidx[b * NPOINT + p] & (NPTS - 1);
    const float* xb = xyz + b * 3 * NPTS;
    const float* nb = nrm + b * 3 * NPTS;
    const float* Xb = Xa  + b * 3 * NPTS;
    const float* Yb = Ya  + b * 3 * NPTS;
    float gx, gy, gz, sq, draw, nnv;
    {
        #pragma clang fp contract(off)
        gx = xb[n]        - xb[fi];
        gy = xb[NPTS + n] - xb[NPTS + fi];
        gz = xb[2*NPTS+n] - xb[2*NPTS+fi];
        sq = gx*gx + gy*gy;
        sq = sq + gz*gz;
        draw = sqrtf(sq + 1e-10f);
        nnv = sqrtf(sq);
    }
    float dmin = draw, dmax = draw;
    #pragma unroll
    for (int m = 1; m < 16; m <<= 1) {
        dmin = fminf(dmin, __shfl_xor(dmin, m, 16));
        dmax = fmaxf(dmax, __shfl_xor(dmax, m, 16));
    }
    float dist;
    {
        #pragma clang fp contract(off)
        dist = (draw - dmin) / ((dmax - dmin) + 1e-10f);
    }
    float nx = nb[n], ny = nb[NPTS+n], nz = nb[2*NPTS+n];
    float Xx = Xb[n], Xy = Xb[NPTS+n], Xz = Xb[2*NPTS+n];
    float Yx = Yb[n], Yy = Yb[NPTS+n], Yz = Yb[2*NPTS+n];
    float g[10];
    g[0]=gx; g[1]=gy; g[2]=gz; g[3]=dist; g[4]=nx; g[5]=ny; g[6]=nz;
    {
        float vs[3][3] = {{nx,ny,nz},{Xx,Xy,Xz},{Yx,Yy,Yz}};
        #pragma unroll
        for (int a = 0; a < 3; ++a) {
            float vx=vs[a][0], vy=vs[a][1], vz=vs[a][2];
            float dot, nv;
            {
                #pragma clang fp contract(off)
                dot = gx*vx + gy*vy; dot = dot + gz*vz;
                float s2 = vx*vx + vy*vy; s2 = s2 + vz*vz;
                nv = sqrtf(s2);
            }
            float cc = dot / (nnv * nv + 1e-8f);
            cc = fminf(1.0f, fmaxf(-1.0f, cc));
            g[7+a] = acosf(cc) / 3.14159274101257324f;
        }
    }
    float h[16];
    #pragma unroll
    for (int i = 0; i < 16; ++i) {
        float a = b1s[i];
        #pragma unroll
        for (int j = 0; j < 10; ++j) a += w1s[i][j] * g[j];
        h[i] = fmaxf(a, 0.0f);
    }
    float e[8]; float mx = -1e30f;
    #pragma unroll
    for (int m = 0; m < 8; ++m) {
        float a = b2s[m];
        #pragma unroll
        for (int j = 0; j < 16; ++j) a += w2s[m][j] * h[j];
        e[m] = a; mx = fmaxf(mx, a);
    }
    float sum = 0.0f;
    #pragma unroll
    for (int m = 0; m < 8; ++m) { e[m] = expf(e[m] - mx); sum += e[m]; }
    #pragma unroll
    for (int m = 0; m < 8; ++m) g_S[(size_t)row * 8 + m] = e[m] / sum;
}

// ---------------------------------------------------------------------------
// PAConv GEMM: O[row,o] = sum_{m,c} (S[row,m]*A[row,c]) * bank[(m,c),o].
// 64x64 tile, Kc=32. A built on the fly in LDS. LDS = 16.9 KB.
// LAYER 0: A = g_pT via knn gather -> g_act1.
// LAYER 1: A = g_act1 -> g_act2.
// LAYER 2: A = g_act2 -> fused max-over-k + transpose into d_out (arg).
// Scratch buffers resolved in DEVICE code (constexpr on LAYER).
// ---------------------------------------------------------------------------
template<int LAYER, int CIN, int COUT>
__global__ __launch_bounds__(256) void gemm_kernel(const float* __restrict__ bank,
                                                   float* __restrict__ dout) {
    const float* __restrict__ A = (LAYER == 0) ? g_pT : (LAYER == 1) ? g_act1 : g_act2;
    float* __restrict__ O = (LAYER == 0) ? g_act1 : (LAYER == 1) ? g_act2 : dout;
    constexpr bool GATHER  = (LAYER == 0);
    constexpr bool FUSEMAX = (LAYER == 2);

    __shared__ float As[32][68];   // [kk][r], padded
    __shared__ float Bs[32][64];   // [kk][o]
    const int t = threadIdx.x;
    const int tx = t & 15, ty = t >> 4;
    const int row0 = blockIdx.x * 64;
    const int o0 = blockIdx.y * 64;
    const int ar = t >> 2, akk = (t & 3) * 8;   // A staging: 1 row, 8 k's
    const int bo = t & 63, bkk = t >> 6;        // B staging
    float acc[4][4] = {};
    const int KDIM = 8 * CIN;

    size_t arow;
    if (GATHER) {
        const int row = row0 + ar;
        const int b = row >> 13;
        const int n = g_knn[row] & (NPTS - 1);
        arow = (size_t)(b * NPTS + n) * 64;
    } else {
        arow = (size_t)(row0 + ar) * CIN;
    }
    const float* Srow = g_S + (size_t)(row0 + ar) * 8;

    for (int k0 = 0; k0 < KDIM; k0 += 32) {
        const int m = k0 / CIN;
        const int c0 = k0 % CIN;
        float sv = Srow[m];
        const float4* fp = reinterpret_cast<const float4*>(A + arow + c0 + akk);
        float4 fa = fp[0], fb = fp[1];
        As[akk+0][ar] = sv * fa.x; As[akk+1][ar] = sv * fa.y;
        As[akk+2][ar] = sv * fa.z; As[akk+3][ar] = sv * fa.w;
        As[akk+4][ar] = sv * fb.x; As[akk+5][ar] = sv * fb.y;
        As[akk+6][ar] = sv * fb.z; As[akk+7][ar] = sv * fb.w;
        #pragma unroll
        for (int j = 0; j < 8; ++j) {
            int kk = bkk + j * 4;
            Bs[kk][bo] = bank[(size_t)(k0 + kk) * COUT + o0 + bo];
        }
        __syncthreads();
        #pragma unroll
        for (int kk = 0; kk < 32; ++kk) {
            float a0 = As[kk][ty*4+0], a1 = As[kk][ty*4+1], a2 = As[kk][ty*4+2], a3 = As[kk][ty*4+3];
            float q0 = Bs[kk][tx*4+0], q1 = Bs[kk][tx*4+1], q2 = Bs[kk][tx*4+2], q3 = Bs[kk][tx*4+3];
            acc[0][0] += a0*q0; acc[0][1] += a0*q1; acc[0][2] += a0*q2; acc[0][3] += a0*q3;
            acc[1][0] += a1*q0; acc[1][1] += a1*q1; acc[1][2] += a1*q2; acc[1][3] += a1*q3;
            acc[2][0] += a2*q0; acc[2][1] += a2*q1; acc[2][2] += a2*q2; acc[2][3] += a2*q3;
            acc[3][0] += a3*q0; acc[3][1] += a3*q1; acc[3][2] += a3*q2; acc[3][3] += a3*q3;
        }
        __syncthreads();
    }

    if (FUSEMAX) {
        // Wave w (= t>>6) holds rows [16w, 16w+16) = all K=16 neighbors of one
        // (b,p). Reduce max over i (4 rows/thread) then lanes ^16, ^32.
        float mj[4];
        #pragma unroll
        for (int j = 0; j < 4; ++j) {
            mj[j] = fmaxf(fmaxf(acc[0][j], acc[1][j]), fmaxf(acc[2][j], acc[3][j]));
            mj[j] = fmaxf(mj[j], __shfl_xor(mj[j], 16));
            mj[j] = fmaxf(mj[j], __shfl_xor(mj[j], 32));
        }
        const int lane = t & 63, w = t >> 6;
        if (lane < 16) {
            const int bp = (row0 >> 4) + w;           // b*512 + p
            const int b = bp >> 9, p = bp & 511;
            #pragma unroll
            for (int j = 0; j < 4; ++j)
                O[(size_t)(b * 256 + o0 + lane * 4 + j) * NPOINT + p] = mj[j];
        }
    } else {
        #pragma unroll
        for (int i = 0; i < 4; ++i) {
            float4 v; v.x = acc[i][0]; v.y = acc[i][1]; v.z = acc[i][2]; v.w = acc[i][3];
            *reinterpret_cast<float4*>(O + (size_t)(row0 + ty*4 + i) * COUT + o0 + tx*4) = v;
        }
    }
}

// Per-channel sum / sumsq over 65536 rows (f32 atomics out).
// COUT=64 -> g_act1 / g_sums[0..128); COUT=128 -> g_act2 / g_sums[256..512).
template<int COUT>
__global__ __launch_bounds__(256) void bn_reduce_kernel() {
    const float* __restrict__ O = (COUT == 64) ? g_act1 : g_act2;
    float* sums = (COUT == 64) ? g_sums : (g_sums + 256);
    const int t = threadIdx.x;
    const int c = t % COUT;
    const int rs = t / COUT;
    const int RL = 256 / COUT;
    const int row0 = blockIdx.x * 256;
    float s = 0.0f, ss = 0.0f;
    for (int r = rs; r < 256; r += RL) {
        float x = O[(size_t)(row0 + r) * COUT + c];
        s += x; ss += x * x;
    }
    __shared__ float ls[256], lss[256];
    ls[t] = s; lss[t] = ss;
    __syncthreads();
    if (t < COUT) {
        for (int i = 1; i < RL; ++i) { s += ls[t + i*COUT]; ss += lss[t + i*COUT]; }
        atomicAdd(&sums[c], s);
        atomicAdd(&sums[COUT + c], ss);
    }
}

// In-place BN + relu (buffers resolved device-side).
template<int COUT>
__global__ __launch_bounds__(256) void bn_apply_kernel(const float* __restrict__ gamma,
                                                       const float* __restrict__ beta) {
    float* O = (COUT == 64) ? g_act1 : g_act2;
    const float* sums = (COUT == 64) ? g_sums : (g_sums + 256);
    const size_t e = (size_t)blockIdx.x * 256 + threadIdx.x;
    const int c = (int)(e % COUT);
    const float inv_n = 1.0f / 65536.0f;
    float mu = sums[c] * inv_n;
    float var = sums[COUT + c] * inv_n - mu * mu;
    var = fmaxf(var, 0.0f);
    float x = O[e];
    float y = (x - mu) / sqrtf(var + 1e-5f) * gamma[c] + beta[c];
    O[e] = fmaxf(y, 0.0f);
}

// Small gathered outputs: new_xyz (fidx), new_norm/new_X/new_Y (knn[...,0]).
__global__ __launch_bounds__(256) void small_out_kernel(const float* __restrict__ xyz,
                                                        const float* __restrict__ nrm,
                                                        const float* __restrict__ Xa,
                                                        const float* __restrict__ Ya,
                                                        float* __restrict__ out) {
    const int t = blockIdx.x * 256 + threadIdx.x;   // 4096 = b*512+p
    const int b = t / NPOINT, p = t % NPOINT;
    const int fi = g_fidx[t] & (NPTS - 1);
    const int n0 = g_knn[t * KNB] & (NPTS - 1);
    #pragma unroll
    for (int a = 0; a < 3; ++a) {
        out[            (b*3 + a) * NPOINT + p] = xyz[(b*3 + a) * NPTS + fi];
        out[12288 +     (b*3 + a) * NPOINT + p] = nrm[(b*3 + a) * NPTS + n0];
        out[24576 +     (b*3 + a) * NPOINT + p] = Xa [(b*3 + a) * NPTS + n0];
        out[36864 +     (b*3 + a) * NPOINT + p] = Ya [(b*3 + a) * NPTS + n0];
    }
}

// ---------------------------------------------------------------------------
extern "C" void kernel_launch(void* const* d_in, const int* in_sizes, int n_in,
                              void* d_out, int out_size, void* d_ws, size_t ws_size,
                              hipStream_t stream) {
    const float* xyz    = (const float*)d_in[0];
    const float* nrm    = (const float*)d_in[1];
    const float* Xa     = (const float*)d_in[2];
    const float* Ya     = (const float*)d_in[3];
    const float* points = (const float*)d_in[4];
    const float* w1_0 = (const float*)d_in[5];  const float* b1_0 = (const float*)d_in[6];
    const float* w2_0 = (const float*)d_in[7];  const float* b2_0 = (const float*)d_in[8];
    const float* bank0 = (const float*)d_in[9];
    const float* g0 = (const float*)d_in[10];   const float* be0 = (const float*)d_in[11];
    const float* w1_1 = (const float*)d_in[12]; const float* b1_1 = (const float*)d_in[13];
    const float* w2_1 = (const float*)d_in[14]; const float* b2_1 = (const float*)d_in[15];
    const float* bank1 = (const float*)d_in[16];
    const float* g1 = (const float*)d_in[17];   const float* be1 = (const float*)d_in[18];
    const float* w1_2 = (const float*)d_in[19]; const float* b1_2 = (const float*)d_in[20];
    const float* w2_2 = (const float*)d_in[21]; const float* b2_2 = (const float*)d_in[22];
    const float* bank2 = (const float*)d_in[23];
    float* out = (float*)d_out;
    (void)d_ws; (void)ws_size; (void)in_sizes; (void)n_in; (void)out_size;

    zero_kernel<<<4, 256, 0, stream>>>();
    fps_kernel<<<NBATCH, 256, 0, stream>>>(xyz);
    knn_kernel<<<1024, 256, 0, stream>>>(xyz);
    transpose_kernel<<<256, 256, 0, stream>>>(points);
    small_out_kernel<<<16, 256, 0, stream>>>(xyz, nrm, Xa, Ya, out);

    // layer 0: cin=64 -> cout=64 (fused gather from g_pT)
    score_kernel<<<256, 256, 0, stream>>>(xyz, nrm, Xa, Ya, w1_0, b1_0, w2_0, b2_0);
    gemm_kernel<0, 64, 64><<<dim3(1024, 1), 256, 0, stream>>>(bank0, out);
    bn_reduce_kernel<64><<<256, 256, 0, stream>>>();
    bn_apply_kernel<64><<<16384, 256, 0, stream>>>(g0, be0);

    // layer 1: cin=64 -> cout=128
    score_kernel<<<256, 256, 0, stream>>>(xyz, nrm, Xa, Ya, w1_1, b1_1, w2_1, b2_1);
    gemm_kernel<1, 64, 128><<<dim3(1024, 2), 256, 0, stream>>>(bank1, out);
    bn_reduce_kernel<128><<<256, 256, 0, stream>>>();
    bn_apply_kernel<128><<<32768, 256, 0, stream>>>(g1, be1);

    // layer 2: cin=128 -> cout=256, fused max-over-k + transpose to d_out
    score_kernel<<<256, 256, 0, stream>>>(xyz, nrm, Xa, Ya, w1_2, b1_2, w2_2, b2_2);
    gemm_kernel<2, 128, 256><<<dim3(1024, 4), 256, 0, stream>>>(bank2, out + 49152);
}

// Round 8
// 879.851 us; speedup vs baseline: 1.8533x; 1.5036x over previous
//
#include <hip/hip_runtime.h>
#include <math.h>

#define NBATCH 8
#define NPTS   2048
#define NPOINT 512
#define KNB    16
#define NROWS  (NBATCH*NPOINT*KNB)   // 65536

typedef unsigned short ushort_t;
typedef unsigned int   uint_t;
typedef __attribute__((ext_vector_type(8))) short  short8;   // 8 bf16 (4 VGPRs)
typedef __attribute__((ext_vector_type(4))) float  f32x4;    // MFMA C/D

// ---------------------------------------------------------------------------
// Scratch in static __device__ globals (zero-init, allocated at module load).
// RULE: referenced ONLY inside device code (host use passes the host shadow
// address -> GPU fault; that was the r1-r4 crash). Fully rewritten each call.
// ---------------------------------------------------------------------------
__device__ __align__(16) int   g_fidx[NBATCH * NPOINT];           //  16 KB
__device__ __align__(16) int   g_knn [NROWS];                     // 256 KB
__device__ __align__(16) float g_sums[1024];                      //   4 KB
__device__ __align__(16) float g_pT  [NBATCH * NPTS * 64];        //   4 MB
__device__ __align__(16) float g_S   [(size_t)NROWS * 8];         //   2 MB
__device__ __align__(16) float g_act1[(size_t)NROWS * 64];        //  16 MB
__device__ __align__(16) float g_act2[(size_t)NROWS * 128];       //  32 MB

// f32 -> bf16 round-to-nearest-even (finite inputs).
__device__ __forceinline__ ushort_t f2bf(float f) {
    uint_t u = __float_as_uint(f);
    return (ushort_t)((u + 0x7FFFu + ((u >> 16) & 1u)) >> 16);
}

// Zero the BN-stats scratch (1024 floats) — must run every call (atomics).
__global__ void zero_kernel() {
    g_sums[blockIdx.x * 256 + threadIdx.x] = 0.0f;
}

// ---------------------------------------------------------------------------
// FPS: one 256-thread block (4 waves) per batch; 8 points per lane in
// registers; coords mirrored in LDS so the centroid read is an LDS broadcast.
// Argmax via packed u64 key (f32bits(dist)<<32 | ~idx): dists >= 0 so f32
// bits are monotonic; ties pick the smaller index (numpy argmax).
// ---------------------------------------------------------------------------
__global__ __launch_bounds__(256, 1) void fps_kernel(const float* __restrict__ xyz) {
    #pragma clang fp contract(off)
    const int b = blockIdx.x;
    const int t = threadIdx.x;
    const int lane = t & 63, w = t >> 6;
    const float* xb = xyz + b * 3 * NPTS;
    __shared__ float s_x[NPTS], s_y[NPTS], s_z[NPTS];
    __shared__ unsigned long long s_key[4];
    float x[8], y[8], z[8], d[8];
    #pragma unroll
    for (int j = 0; j < 8; ++j) {
        int p = j * 256 + t;
        float vx = xb[p], vy = xb[NPTS + p], vz = xb[2*NPTS + p];
        x[j] = vx; y[j] = vy; z[j] = vz;
        s_x[p] = vx; s_y[p] = vy; s_z[p] = vz;
        d[j] = 1e10f;
    }
    __syncthreads();
    int far = 0;
    for (int i = 0; i < NPOINT; ++i) {
        if (t == 0) g_fidx[b * NPOINT + i] = far;
        float cx = s_x[far], cy = s_y[far], cz = s_z[far];
        float best = -1.0f; int bi = 0;
        #pragma unroll
        for (int j = 0; j < 8; ++j) {
            float dx = x[j] - cx;
            float dy = y[j] - cy;
            float dz = z[j] - cz;
            float dd = dx*dx + dy*dy;
            dd = dd + dz*dz;
            float dn = fminf(d[j], dd);
            d[j] = dn;
            if (dn > best) { best = dn; bi = j * 256 + t; }
        }
        unsigned long long key =
            (((unsigned long long)__float_as_uint(best)) << 32) | (unsigned)(~bi);
        #pragma unroll
        for (int m = 1; m < 64; m <<= 1) {
            unsigned long long ok = __shfl_xor(key, m);
            if (ok > key) key = ok;
        }
        if (lane == 0) s_key[w] = key;
        __syncthreads();
        unsigned long long k0 = s_key[0], k1 = s_key[1];
        unsigned long long k2 = s_key[2], k3 = s_key[3];
        if (k1 > k0) k0 = k1;
        if (k3 > k2) k2 = k3;
        if (k2 > k0) k0 = k2;
        far = (int)(~(unsigned)k0) & (NPTS - 1);
        __syncthreads();
    }
}

// ---------------------------------------------------------------------------
// KNN: one wave per query. Expanded |a|^2+|b|^2-2ab form (contract off);
// 16 rounds of wave-min with index tie-break.
// ---------------------------------------------------------------------------
__global__ __launch_bounds__(256) void knn_kernel(const float* __restrict__ xyz) {
    #pragma clang fp contract(off)
    const int wave = blockIdx.x * 4 + (threadIdx.x >> 6);
    const int lane = threadIdx.x & 63;
    const int b = wave >> 9;
    const float* xb = xyz + b * 3 * NPTS;
    const int fi = g_fidx[wave] & (NPTS - 1);
    float ax = xb[fi];
    float ay = xb[NPTS + fi];
    float az = xb[2*NPTS + fi];
    float sa = ax*ax + ay*ay; sa = sa + az*az;
    float d[32];
    #pragma unroll
    for (int j = 0; j < 32; ++j) {
        int p = j * 64 + lane;
        float bx = xb[p];
        float by = xb[NPTS + p];
        float bz = xb[2*NPTS + p];
        float sb = bx*bx + by*by; sb = sb + bz*bz;
        float dot = ax*bx + ay*by; dot = dot + az*bz;
        float t1 = sa + sb;
        float t2 = 2.0f * dot;
        d[j] = t1 - t2;
    }
    for (int r = 0; r < KNB; ++r) {
        float best = 1e30f; int bi = 0x7fffffff;
        #pragma unroll
        for (int j = 0; j < 32; ++j) {
            if (d[j] < best) { best = d[j]; bi = j * 64 + lane; }
        }
        #pragma unroll
        for (int m = 32; m >= 1; m >>= 1) {
            float ov = __shfl_xor(best, m);
            int   oi = __shfl_xor(bi, m);
            if (ov < best || (ov == best && oi < bi)) { best = ov; bi = oi; }
        }
        bi &= (NPTS - 1);
        if (lane == 0) g_knn[wave * KNB + r] = bi;
        int rl = bi & 63, rs = bi >> 6;
        if (lane == rl) {
            #pragma unroll
            for (int j = 0; j < 32; ++j) if (j == rs) d[j] = 1e30f;
        }
    }
}

// ---------------------------------------------------------------------------
// Transpose points [b][c][n] -> [b][n][c] (f32) for coalesced gather.
// ---------------------------------------------------------------------------
__global__ __launch_bounds__(256) void transpose_kernel(const float* __restrict__ points) {
    __shared__ float tile[64][65];
    const int blk = blockIdx.x;
    const int b = blk >> 5;
    const int n0 = (blk & 31) * 64;
    const int t = threadIdx.x;
    const int lane = t & 63, q = t >> 6;
    #pragma unroll
    for (int i = 0; i < 16; ++i) {
        int c = q * 16 + i;
        tile[c][lane] = points[(b * 64 + c) * NPTS + n0 + lane];
    }
    __syncthreads();
    #pragma unroll
    for (int i = 0; i < 16; ++i) {
        int n = q * 16 + i;
        g_pT[(size_t)(b * NPTS + n0 + n) * 64 + lane] = tile[lane][n];
    }
}

// ---------------------------------------------------------------------------
// Geometry + ONE layer's scoring MLP. One thread per (b,p,k).
// ---------------------------------------------------------------------------
__global__ __launch_bounds__(256) void score_kernel(
    const float* __restrict__ xyz, const float* __restrict__ nrm,
    const float* __restrict__ Xa, const float* __restrict__ Ya,
    const float* __restrict__ w1, const float* __restrict__ b1,
    const float* __restrict__ w2, const float* __restrict__ b2) {
    __shared__ float w1s[16][10];
    __shared__ float b1s[16];
    __shared__ float w2s[8][16];
    __shared__ float b2s[8];
    const int t = threadIdx.x;
    if (t < 160) w1s[t / 10][t % 10] = w1[t];
    if (t < 16)  b1s[t] = b1[t];
    if (t < 128) w2s[t / 16][t % 16] = w2[t];
    if (t < 8)   b2s[t] = b2[t];
    __syncthreads();
    const int row = blockIdx.x * 256 + t;
    const int b = row >> 13;
    const int p = (row >> 4) & 511;
    const int n = g_knn[row] & (NPTS - 1);
    const int fi = g_fidx[b * NPOINT + p] & (NPTS - 1);
    const float* xb = xyz + b * 3 * NPTS;
    const float* nb = nrm + b * 3 * NPTS;
    const float* Xb = Xa  + b * 3 * NPTS;
    const float* Yb = Ya  + b * 3 * NPTS;
    float gx, gy, gz, sq, draw, nnv;
    {
        #pragma clang fp contract(off)
        gx = xb[n]        - xb[fi];
        gy = xb[NPTS + n] - xb[NPTS + fi];
        gz = xb[2*NPTS+n] - xb[2*NPTS+fi];
        sq = gx*gx + gy*gy;
        sq = sq + gz*gz;
        draw = sqrtf(sq + 1e-10f);
        nnv = sqrtf(sq);
    }
    float dmin = draw, dmax = draw;
    #pragma unroll
    for (int m = 1; m < 16; m <<= 1) {
        dmin = fminf(dmin, __shfl_xor(dmin, m, 16));
        dmax = fmaxf(dmax, __shfl_xor(dmax, m, 16));
    }
    float dist;
    {
        #pragma clang fp contract(off)
        dist = (draw - dmin) / ((dmax - dmin) + 1e-10f);
    }
    float nx = nb[n], ny = nb[NPTS+n], nz = nb[2*NPTS+n];
    float Xx = Xb[n], Xy = Xb[NPTS+n], Xz = Xb[2*NPTS+n];
    float Yx = Yb[n], Yy = Yb[NPTS+n], Yz = Yb[2*NPTS+n];
    float g[10];
    g[0]=gx; g[1]=gy; g[2]=gz; g[3]=dist; g[4]=nx; g[5]=ny; g[6]=nz;
    {
        float vs[3][3] = {{nx,ny,nz},{Xx,Xy,Xz},{Yx,Yy,Yz}};
        #pragma unroll
        for (int a = 0; a < 3; ++a) {
            float vx=vs[a][0], vy=vs[a][1], vz=vs[a][2];
            float dot, nv;
            {
                #pragma clang fp contract(off)
                dot = gx*vx + gy*vy; dot = dot + gz*vz;
                float s2 = vx*vx + vy*vy; s2 = s2 + vz*vz;
                nv = sqrtf(s2);
            }
            float cc = dot / (nnv * nv + 1e-8f);
            cc = fminf(1.0f, fmaxf(-1.0f, cc));
            g[7+a] = acosf(cc) / 3.14159274101257324f;
        }
    }
    float h[16];
    #pragma unroll
    for (int i = 0; i < 16; ++i) {
        float a = b1s[i];
        #pragma unroll
        for (int j = 0; j < 10; ++j) a += w1s[i][j] * g[j];
        h[i] = fmaxf(a, 0.0f);
    }
    float e[8]; float mx = -1e30f;
    #pragma unroll
    for (int m = 0; m < 8; ++m) {
        float a = b2s[m];
        #pragma unroll
        for (int j = 0; j < 16; ++j) a += w2s[m][j] * h[j];
        e[m] = a; mx = fmaxf(mx, a);
    }
    float sum = 0.0f;
    #pragma unroll
    for (int m = 0; m < 8; ++m) { e[m] = expf(e[m] - mx); sum += e[m]; }
    #pragma unroll
    for (int m = 0; m < 8; ++m) g_S[(size_t)row * 8 + m] = e[m] / sum;
}

// ---------------------------------------------------------------------------
// MFMA PAConv GEMM: O[row,o] = sum_{m,c} (S[row,m]*A[row,c]) * bank[(m,c),o]
// using v_mfma_f32_16x16x32_bf16. Block = 4 waves = 64 rows x full COUT.
// A-tile (S*F, RNE bf16) in LDS [64][36]; B-tile transposed [COUT][36]
// (pitch 36 bf16 = 72 B: 8B-aligned fragments, 2-way banks).
// Fragment layouts (m120/m89-verified): A[m=lane&15][k=quad*8+j],
// B[k=quad*8+j][n=lane&15], C/D[col=lane&15][row=quad*4+reg].
// LAYER 0: rows gathered via g_knn from g_pT -> g_act1.
// LAYER 1: g_act1 -> g_act2.  LAYER 2: g_act2 -> fused max-k to dout.
// ---------------------------------------------------------------------------
template<int LAYER, int CIN, int COUT>
__global__ __launch_bounds__(256) void gemm_kernel(const float* __restrict__ bank,
                                                   float* __restrict__ dout) {
    const float* __restrict__ A = (LAYER == 0) ? g_pT : (LAYER == 1) ? g_act1 : g_act2;
    float* __restrict__ O = (LAYER == 0) ? g_act1 : (LAYER == 1) ? g_act2 : dout;
    constexpr int NT = COUT / 16;          // n-tiles per wave
    __shared__ ushort_t As[64][36];
    __shared__ ushort_t Bs[COUT][36];

    const int t = threadIdx.x;
    const int lane = t & 63, w = t >> 6;
    const int q = lane >> 4, nlo = lane & 15;
    const int row0 = blockIdx.x * 64;

    // A staging assignment: 4 threads per row, 8 k's each
    const int arow_i = t >> 2, acg = t & 3;
    size_t arow;
    if (LAYER == 0) {
        const int row = row0 + arow_i;
        const int b = row >> 13;
        const int n = g_knn[row] & (NPTS - 1);
        arow = (size_t)(b * NPTS + n) * 64;
    } else {
        arow = (size_t)(row0 + arow_i) * CIN;
    }
    // B staging assignment: n = bn + no, k-group kg (8 k's each)
    const int bn = t & 63, bkg = t >> 6;

    f32x4 acc[NT];
    #pragma unroll
    for (int i = 0; i < NT; ++i) acc[i] = (f32x4){0.f, 0.f, 0.f, 0.f};

    for (int m = 0; m < 8; ++m) {
        const float sv = g_S[(size_t)(row0 + arow_i) * 8 + m];
        for (int c0 = 0; c0 < CIN; c0 += 32) {
            // ---- stage A (S*F -> bf16) ----
            {
                const float* ap = A + arow + c0 + acg * 8;
                float4 fa = *reinterpret_cast<const float4*>(ap);
                float4 fb = *reinterpret_cast<const float4*>(ap + 4);
                uint_t p0 = (uint_t)f2bf(sv*fa.x) | ((uint_t)f2bf(sv*fa.y) << 16);
                uint_t p1 = (uint_t)f2bf(sv*fa.z) | ((uint_t)f2bf(sv*fa.w) << 16);
                uint_t p2 = (uint_t)f2bf(sv*fb.x) | ((uint_t)f2bf(sv*fb.y) << 16);
                uint_t p3 = (uint_t)f2bf(sv*fb.z) | ((uint_t)f2bf(sv*fb.w) << 16);
                uint_t* dst = reinterpret_cast<uint_t*>(&As[arow_i][acg * 8]);
                dst[0] = p0; dst[1] = p1; dst[2] = p2; dst[3] = p3;
            }
            // ---- stage B transposed (bank -> bf16) ----
            {
                const int k0 = m * CIN + c0;
                #pragma unroll
                for (int no = 0; no < COUT; no += 64) {
                    const int n = no + bn;
                    #pragma unroll
                    for (int j = 0; j < 8; j += 2) {
                        float v0 = bank[(size_t)(k0 + bkg*8 + j    ) * COUT + n];
                        float v1 = bank[(size_t)(k0 + bkg*8 + j + 1) * COUT + n];
                        uint_t pk = (uint_t)f2bf(v0) | ((uint_t)f2bf(v1) << 16);
                        *reinterpret_cast<uint_t*>(&Bs[n][bkg*8 + j]) = pk;
                    }
                }
            }
            __syncthreads();
            // ---- MFMA ----
            union FragU { uint2 u2[2]; short8 s; } af;
            af.u2[0] = *reinterpret_cast<const uint2*>(&As[w*16 + nlo][q*8]);
            af.u2[1] = *reinterpret_cast<const uint2*>(&As[w*16 + nlo][q*8 + 4]);
            #pragma unroll
            for (int nt = 0; nt < NT; ++nt) {
                FragU bf;
                bf.u2[0] = *reinterpret_cast<const uint2*>(&Bs[nt*16 + nlo][q*8]);
                bf.u2[1] = *reinterpret_cast<const uint2*>(&Bs[nt*16 + nlo][q*8 + 4]);
                acc[nt] = __builtin_amdgcn_mfma_f32_16x16x32_bf16(af.s, bf.s, acc[nt], 0, 0, 0);
            }
            __syncthreads();
        }
    }

    if (LAYER == 2) {
        // wave w holds rows w*16..w*16+15 = all K=16 neighbors of one (b,p)
        const int bp = (row0 >> 4) + w;
        const int b = bp >> 9, p = bp & 511;
        #pragma unroll
        for (int nt = 0; nt < NT; ++nt) {
            float mv = fmaxf(fmaxf(acc[nt][0], acc[nt][1]), fmaxf(acc[nt][2], acc[nt][3]));
            mv = fmaxf(mv, __shfl_xor(mv, 16));
            mv = fmaxf(mv, __shfl_xor(mv, 32));
            if (lane < 16)
                O[(size_t)(b * 256 + nt*16 + nlo) * NPOINT + p] = mv;
        }
    } else {
        #pragma unroll
        for (int nt = 0; nt < NT; ++nt)
            #pragma unroll
            for (int r2 = 0; r2 < 4; ++r2)
                O[(size_t)(row0 + w*16 + q*4 + r2) * COUT + nt*16 + nlo] = acc[nt][r2];
    }
}

// Per-channel sum / sumsq over 65536 rows (f32 atomics out).
template<int COUT>
__global__ __launch_bounds__(256) void bn_reduce_kernel() {
    const float* __restrict__ O = (COUT == 64) ? g_act1 : g_act2;
    float* sums = (COUT == 64) ? g_sums : (g_sums + 256);
    const int t = threadIdx.x;
    const int c = t % COUT;
    const int rs = t / COUT;
    const int RL = 256 / COUT;
    const int row0 = blockIdx.x * 256;
    float s = 0.0f, ss = 0.0f;
    for (int r = rs; r < 256; r += RL) {
        float x = O[(size_t)(row0 + r) * COUT + c];
        s += x; ss += x * x;
    }
    __shared__ float ls[256], lss[256];
    ls[t] = s; lss[t] = ss;
    __syncthreads();
    if (t < COUT) {
        for (int i = 1; i < RL; ++i) { s += ls[t + i*COUT]; ss += lss[t + i*COUT]; }
        atomicAdd(&sums[c], s);
        atomicAdd(&sums[COUT + c], ss);
    }
}

// In-place BN + relu (buffers resolved device-side).
template<int COUT>
__global__ __launch_bounds__(256) void bn_apply_kernel(const float* __restrict__ gamma,
                                                       const float* __restrict__ beta) {
    float* O = (COUT == 64) ? g_act1 : g_act2;
    const float* sums = (COUT == 64) ? g_sums : (g_sums + 256);
    const size_t e = (size_t)blockIdx.x * 256 + threadIdx.x;
    const int c = (int)(e % COUT);
    const float inv_n = 1.0f / 65536.0f;
    float mu = sums[c] * inv_n;
    float var = sums[COUT + c] * inv_n - mu * mu;
    var = fmaxf(var, 0.0f);
    float x = O[e];
    float y = (x - mu) / sqrtf(var + 1e-5f) * gamma[c] + beta[c];
    O[e] = fmaxf(y, 0.0f);
}

// Small gathered outputs: new_xyz (fidx), new_norm/new_X/new_Y (knn[...,0]).
__global__ __launch_bounds__(256) void small_out_kernel(const float* __restrict__ xyz,
                                                        const float* __restrict__ nrm,
                                                        const float* __restrict__ Xa,
                                                        const float* __restrict__ Ya,
                                                        float* __restrict__ out) {
    const int t = blockIdx.x * 256 + threadIdx.x;
    const int b = t / NPOINT, p = t % NPOINT;
    const int fi = g_fidx[t] & (NPTS - 1);
    const int n0 = g_knn[t * KNB] & (NPTS - 1);
    #pragma unroll
    for (int a = 0; a < 3; ++a) {
        out[            (b*3 + a) * NPOINT + p] = xyz[(b*3 + a) * NPTS + fi];
        out[12288 +     (b*3 + a) * NPOINT + p] = nrm[(b*3 + a) * NPTS + n0];
        out[24576 +     (b*3 + a) * NPOINT + p] = Xa [(b*3 + a) * NPTS + n0];
        out[36864 +     (b*3 + a) * NPOINT + p] = Ya [(b*3 + a) * NPTS + n0];
    }
}

// ---------------------------------------------------------------------------
extern "C" void kernel_launch(void* const* d_in, const int* in_sizes, int n_in,
                              void* d_out, int out_size, void* d_ws, size_t ws_size,
                              hipStream_t stream) {
    const float* xyz    = (const float*)d_in[0];
    const float* nrm    = (const float*)d_in[1];
    const float* Xa     = (const float*)d_in[2];
    const float* Ya     = (const float*)d_in[3];
    const float* points = (const float*)d_in[4];
    const float* w1_0 = (const float*)d_in[5];  const float* b1_0 = (const float*)d_in[6];
    const float* w2_0 = (const float*)d_in[7];  const float* b2_0 = (const float*)d_in[8];
    const float* bank0 = (const float*)d_in[9];
    const float* g0 = (const float*)d_in[10];   const float* be0 = (const float*)d_in[11];
    const float* w1_1 = (const float*)d_in[12]; const float* b1_1 = (const float*)d_in[13];
    const float* w2_1 = (const float*)d_in[14]; const float* b2_1 = (const float*)d_in[15];
    const float* bank1 = (const float*)d_in[16];
    const float* g1 = (const float*)d_in[17];   const float* be1 = (const float*)d_in[18];
    const float* w1_2 = (const float*)d_in[19]; const float* b1_2 = (const float*)d_in[20];
    const float* w2_2 = (const float*)d_in[21]; const float* b2_2 = (const float*)d_in[22];
    const float* bank2 = (const float*)d_in[23];
    float* out = (float*)d_out;
    (void)d_ws; (void)ws_size; (void)in_sizes; (void)n_in; (void)out_size;

    zero_kernel<<<4, 256, 0, stream>>>();
    fps_kernel<<<NBATCH, 256, 0, stream>>>(xyz);
    knn_kernel<<<1024, 256, 0, stream>>>(xyz);
    transpose_kernel<<<256, 256, 0, stream>>>(points);
    small_out_kernel<<<16, 256, 0, stream>>>(xyz, nrm, Xa, Ya, out);

    // layer 0: cin=64 -> cout=64 (fused gather from g_pT)
    score_kernel<<<256, 256, 0, stream>>>(xyz, nrm, Xa, Ya, w1_0, b1_0, w2_0, b2_0);
    gemm_kernel<0, 64, 64><<<1024, 256, 0, stream>>>(bank0, out);
    bn_reduce_kernel<64><<<256, 256, 0, stream>>>();
    bn_apply_kernel<64><<<16384, 256, 0, stream>>>(g0, be0);

    // layer 1: cin=64 -> cout=128
    score_kernel<<<256, 256, 0, stream>>>(xyz, nrm, Xa, Ya, w1_1, b1_1, w2_1, b2_1);
    gemm_kernel<1, 64, 128><<<1024, 256, 0, stream>>>(bank1, out);
    bn_reduce_kernel<128><<<256, 256, 0, stream>>>();
    bn_apply_kernel<128><<<32768, 256, 0, stream>>>(g1, be1);

    // layer 2: cin=128 -> cout=256, fused max-over-k + transpose to d_out
    score_kernel<<<256, 256, 0, stream>>>(xyz, nrm, Xa, Ya, w1_2, b1_2, w2_2, b2_2);
    gemm_kernel<2, 128, 256><<<1024, 256, 0, stream>>>(bank2, out + 49152);
}

// Round 9
// 813.692 us; speedup vs baseline: 2.0040x; 1.0813x over previous
//
#include <hip/hip_runtime.h>
#include <math.h>

#define NBATCH 8
#define NPTS   2048
#define NPOINT 512
#define KNB    16
#define NROWS  (NBATCH*NPOINT*KNB)   // 65536

typedef unsigned short ushort_t;
typedef unsigned int   uint_t;
typedef unsigned long long ull_t;
typedef __attribute__((ext_vector_type(8))) short  short8;   // 8 bf16 (4 VGPRs)
typedef __attribute__((ext_vector_type(4))) float  f32x4;    // MFMA C/D

// ---------------------------------------------------------------------------
// Scratch in static __device__ globals. Referenced ONLY in device code.
// ---------------------------------------------------------------------------
__device__ __align__(16) int   g_fidx[NBATCH * NPOINT];           //  16 KB
__device__ __align__(16) int   g_knn [NROWS];                     // 256 KB
__device__ __align__(16) float g_sums[1024];                      //   4 KB
__device__ __align__(16) float g_pT  [NBATCH * NPTS * 64];        //   4 MB
__device__ __align__(16) float g_S   [(size_t)3 * NROWS * 8];     //   6 MB (3 layers)
__device__ __align__(16) float g_act1[(size_t)NROWS * 64];        //  16 MB (raw gemm0 out)
__device__ __align__(16) float g_act2[(size_t)NROWS * 128];       //  32 MB (raw gemm1 out)

// f32 -> bf16 round-to-nearest-even (finite inputs).
__device__ __forceinline__ ushort_t f2bf(float f) {
    uint_t u = __float_as_uint(f);
    return (ushort_t)((u + 0x7FFFu + ((u >> 16) & 1u)) >> 16);
}

// ---------------------------------------------------------------------------
// front_kernel: blocks 0-7 = FPS (one block per batch), 8-263 = transpose
// points [b][c][n]->[b][n][c], 264 = zero g_sums. Transpose/zero hide under
// the FPS serial chain.
// FPS: 4 waves, 8 pts/lane in regs, coords mirrored in LDS. Argmax key =
// (f32bits(dist)<<32)|~idx (dist>=0 -> monotone bits; ties -> smaller idx =
// numpy argmax). ONE barrier per iteration via parity-double-buffered s_key:
// iter i writes slot i&1 pre-barrier, reads post-barrier; iter i+2's write of
// the same slot is after barrier i+1, which follows every read at iter i.
// ---------------------------------------------------------------------------
__global__ __launch_bounds__(256) void front_kernel(const float* __restrict__ xyz,
                                                    const float* __restrict__ points) {
    __shared__ float smem[3 * NPTS + 16];
    const int bid = blockIdx.x;
    const int t = threadIdx.x;

    if (bid >= NBATCH) {
        if (bid < NBATCH + 256) {
            // ---- transpose ----
            float (*tile)[65] = reinterpret_cast<float(*)[65]>(smem);
            const int blk = bid - NBATCH;
            const int b = blk >> 5;
            const int n0 = (blk & 31) * 64;
            const int lane = t & 63, q = t >> 6;
            #pragma unroll
            for (int i = 0; i < 16; ++i) {
                int c = q * 16 + i;
                tile[c][lane] = points[(b * 64 + c) * NPTS + n0 + lane];
            }
            __syncthreads();
            #pragma unroll
            for (int i = 0; i < 16; ++i) {
                int n = q * 16 + i;
                g_pT[(size_t)(b * NPTS + n0 + n) * 64 + lane] = tile[lane][n];
            }
        } else {
            // ---- zero BN-stats (must run every call: atomics accumulate) ----
            #pragma unroll
            for (int j = 0; j < 4; ++j) g_sums[j * 256 + t] = 0.0f;
        }
        return;
    }

    // ---- FPS ----
    {
        #pragma clang fp contract(off)
        const int b = bid;
        const int lane = t & 63, w4 = t >> 6;
        const float* xb = xyz + b * 3 * NPTS;
        float* s_x = smem;
        float* s_y = smem + NPTS;
        float* s_z = smem + 2 * NPTS;
        ull_t* s_key = reinterpret_cast<ull_t*>(smem + 3 * NPTS);  // 8 slots
        float x[8], y[8], z[8], d[8];
        #pragma unroll
        for (int j = 0; j < 8; ++j) {
            int p = j * 256 + t;
            float vx = xb[p], vy = xb[NPTS + p], vz = xb[2*NPTS + p];
            x[j] = vx; y[j] = vy; z[j] = vz;
            s_x[p] = vx; s_y[p] = vy; s_z[p] = vz;
            d[j] = 1e10f;
        }
        __syncthreads();
        int far = 0;
        for (int i = 0; i < NPOINT; ++i) {
            if (t == 0) g_fidx[b * NPOINT + i] = far;
            float cx = s_x[far], cy = s_y[far], cz = s_z[far];
            float best = -1.0f; int bi = 0;
            #pragma unroll
            for (int j = 0; j < 8; ++j) {
                float dx = x[j] - cx;
                float dy = y[j] - cy;
                float dz = z[j] - cz;
                float dd = dx*dx + dy*dy;   // ((dx^2+dy^2)+dz^2) like np
                dd = dd + dz*dz;
                float dn = fminf(d[j], dd);
                d[j] = dn;
                if (dn > best) { best = dn; bi = j * 256 + t; }  // strict >
            }
            ull_t key = (((ull_t)__float_as_uint(best)) << 32) | (uint_t)(~bi);
            #pragma unroll
            for (int m = 1; m < 64; m <<= 1) {
                ull_t ok = __shfl_xor(key, m);
                if (ok > key) key = ok;
            }
            if (lane == 0) s_key[((i & 1) << 2) + w4] = key;
            __syncthreads();
            const ull_t* kb = s_key + ((i & 1) << 2);
            ull_t k0 = kb[0], k1 = kb[1], k2 = kb[2], k3 = kb[3];
            if (k1 > k0) k0 = k1;
            if (k3 > k2) k2 = k3;
            if (k2 > k0) k0 = k2;
            far = (int)(~(uint_t)k0) & (NPTS - 1);
        }
    }
}

// ---------------------------------------------------------------------------
// KNN: one wave per query. Expanded |a|^2+|b|^2-2ab form (contract off);
// 16 rounds of wave-min with index tie-break.
// ---------------------------------------------------------------------------
__global__ __launch_bounds__(256) void knn_kernel(const float* __restrict__ xyz) {
    #pragma clang fp contract(off)
    const int wave = blockIdx.x * 4 + (threadIdx.x >> 6);
    const int lane = threadIdx.x & 63;
    const int b = wave >> 9;
    const float* xb = xyz + b * 3 * NPTS;
    const int fi = g_fidx[wave] & (NPTS - 1);
    float ax = xb[fi];
    float ay = xb[NPTS + fi];
    float az = xb[2*NPTS + fi];
    float sa = ax*ax + ay*ay; sa = sa + az*az;
    float d[32];
    #pragma unroll
    for (int j = 0; j < 32; ++j) {
        int p = j * 64 + lane;
        float bx = xb[p];
        float by = xb[NPTS + p];
        float bz = xb[2*NPTS + p];
        float sb = bx*bx + by*by; sb = sb + bz*bz;
        float dot = ax*bx + ay*by; dot = dot + az*bz;
        float t1 = sa + sb;
        float t2 = 2.0f * dot;
        d[j] = t1 - t2;
    }
    for (int r = 0; r < KNB; ++r) {
        float best = 1e30f; int bi = 0x7fffffff;
        #pragma unroll
        for (int j = 0; j < 32; ++j) {
            if (d[j] < best) { best = d[j]; bi = j * 64 + lane; }
        }
        #pragma unroll
        for (int m = 32; m >= 1; m >>= 1) {
            float ov = __shfl_xor(best, m);
            int   oi = __shfl_xor(bi, m);
            if (ov < best || (ov == best && oi < bi)) { best = ov; bi = oi; }
        }
        bi &= (NPTS - 1);
        if (lane == 0) g_knn[wave * KNB + r] = bi;
        int rl = bi & 63, rs = bi >> 6;
        if (lane == rl) {
            #pragma unroll
            for (int j = 0; j < 32; ++j) if (j == rs) d[j] = 1e30f;
        }
    }
}

// ---------------------------------------------------------------------------
// score3_kernel: blocks 0-255 compute geometry ONCE and all THREE scoring
// MLPs (S0,S1,S2); blocks 256-271 do the small gathered outputs.
// ---------------------------------------------------------------------------
__global__ __launch_bounds__(256) void score3_kernel(
    const float* __restrict__ xyz, const float* __restrict__ nrm,
    const float* __restrict__ Xa, const float* __restrict__ Ya,
    const float* __restrict__ w1_0, const float* __restrict__ b1_0,
    const float* __restrict__ w2_0, const float* __restrict__ b2_0,
    const float* __restrict__ w1_1, const float* __restrict__ b1_1,
    const float* __restrict__ w2_1, const float* __restrict__ b2_1,
    const float* __restrict__ w1_2, const float* __restrict__ b1_2,
    const float* __restrict__ w2_2, const float* __restrict__ b2_2,
    float* __restrict__ out) {
    const int bid = blockIdx.x;
    const int t = threadIdx.x;
    if (bid >= 256) {
        // ---- small outputs: new_xyz (fidx), new_norm/X/Y (knn[...,0]) ----
        const int g = (bid - 256) * 256 + t;       // b*512+p
        const int b = g / NPOINT, p = g % NPOINT;
        const int fi = g_fidx[g] & (NPTS - 1);
        const int n0 = g_knn[g * KNB] & (NPTS - 1);
        #pragma unroll
        for (int a = 0; a < 3; ++a) {
            out[            (b*3 + a) * NPOINT + p] = xyz[(b*3 + a) * NPTS + fi];
            out[12288 +     (b*3 + a) * NPOINT + p] = nrm[(b*3 + a) * NPTS + n0];
            out[24576 +     (b*3 + a) * NPOINT + p] = Xa [(b*3 + a) * NPTS + n0];
            out[36864 +     (b*3 + a) * NPOINT + p] = Ya [(b*3 + a) * NPTS + n0];
        }
        return;
    }
    __shared__ float w1s[3][16][10];
    __shared__ float b1s[3][16];
    __shared__ float w2s[3][8][16];
    __shared__ float b2s[3][8];
    {
        const float* w1p[3] = {w1_0, w1_1, w1_2};
        const float* b1p[3] = {b1_0, b1_1, b1_2};
        const float* w2p[3] = {w2_0, w2_1, w2_2};
        const float* b2p[3] = {b2_0, b2_1, b2_2};
        #pragma unroll
        for (int l = 0; l < 3; ++l) {
            if (t < 160) w1s[l][t / 10][t % 10] = w1p[l][t];
            if (t < 16)  b1s[l][t] = b1p[l][t];
            if (t < 128) w2s[l][t / 16][t % 16] = w2p[l][t];
            if (t < 8)   b2s[l][t] = b2p[l][t];
        }
    }
    __syncthreads();
    const int row = bid * 256 + t;
    const int b = row >> 13;
    const int p = (row >> 4) & 511;
    const int n = g_knn[row] & (NPTS - 1);
    const int fi = g_fidx[b * NPOINT + p] & (NPTS - 1);
    const float* xb = xyz + b * 3 * NPTS;
    const float* nb = nrm + b * 3 * NPTS;
    const float* Xb = Xa  + b * 3 * NPTS;
    const float* Yb = Ya  + b * 3 * NPTS;
    float gx, gy, gz, sq, draw, nnv;
    {
        #pragma clang fp contract(off)
        gx = xb[n]        - xb[fi];
        gy = xb[NPTS + n] - xb[NPTS + fi];
        gz = xb[2*NPTS+n] - xb[2*NPTS+fi];
        sq = gx*gx + gy*gy;
        sq = sq + gz*gz;
        draw = sqrtf(sq + 1e-10f);
        nnv = sqrtf(sq);
    }
    float dmin = draw, dmax = draw;
    #pragma unroll
    for (int m = 1; m < 16; m <<= 1) {
        dmin = fminf(dmin, __shfl_xor(dmin, m, 16));
        dmax = fmaxf(dmax, __shfl_xor(dmax, m, 16));
    }
    float dist;
    {
        #pragma clang fp contract(off)
        dist = (draw - dmin) / ((dmax - dmin) + 1e-10f);
    }
    float nx = nb[n], ny = nb[NPTS+n], nz = nb[2*NPTS+n];
    float Xx = Xb[n], Xy = Xb[NPTS+n], Xz = Xb[2*NPTS+n];
    float Yx = Yb[n], Yy = Yb[NPTS+n], Yz = Yb[2*NPTS+n];
    float g[10];
    g[0]=gx; g[1]=gy; g[2]=gz; g[3]=dist; g[4]=nx; g[5]=ny; g[6]=nz;
    {
        float vs[3][3] = {{nx,ny,nz},{Xx,Xy,Xz},{Yx,Yy,Yz}};
        #pragma unroll
        for (int a = 0; a < 3; ++a) {
            float vx=vs[a][0], vy=vs[a][1], vz=vs[a][2];
            float dot, nv;
            {
                #pragma clang fp contract(off)
                dot = gx*vx + gy*vy; dot = dot + gz*vz;
                float s2 = vx*vx + vy*vy; s2 = s2 + vz*vz;
                nv = sqrtf(s2);
            }
            float cc = dot / (nnv * nv + 1e-8f);
            cc = fminf(1.0f, fmaxf(-1.0f, cc));
            g[7+a] = acosf(cc) / 3.14159274101257324f;
        }
    }
    #pragma unroll
    for (int l = 0; l < 3; ++l) {
        float h[16];
        #pragma unroll
        for (int i = 0; i < 16; ++i) {
            float a = b1s[l][i];
            #pragma unroll
            for (int j = 0; j < 10; ++j) a += w1s[l][i][j] * g[j];
            h[i] = fmaxf(a, 0.0f);
        }
        float e[8]; float mx = -1e30f;
        #pragma unroll
        for (int m = 0; m < 8; ++m) {
            float a = b2s[l][m];
            #pragma unroll
            for (int j = 0; j < 16; ++j) a += w2s[l][m][j] * h[j];
            e[m] = a; mx = fmaxf(mx, a);
        }
        float sum = 0.0f;
        #pragma unroll
        for (int m = 0; m < 8; ++m) { e[m] = expf(e[m] - mx); sum += e[m]; }
        #pragma unroll
        for (int m = 0; m < 8; ++m)
            g_S[(size_t)l * NROWS * 8 + (size_t)row * 8 + m] = e[m] / sum;
    }
}

// ---------------------------------------------------------------------------
// MFMA PAConv GEMM with fused BN:
//  - LAYER>=1 staging applies previous layer's BN+relu on the fly
//    (y = max(x*scale[c]+shift[c],0)) from scale/shift precomputed in LDS.
//  - LAYER<2 epilogue accumulates per-channel sum/sumsq of the RAW output
//    into g_sums via one atomicAdd per channel per block.
// Core MFMA identical to the verified r8 kernel.
// ---------------------------------------------------------------------------
template<int LAYER, int CIN, int COUT>
__global__ __launch_bounds__(256) void gemm_kernel(const float* __restrict__ bank,
                                                   const float* __restrict__ gamma,
                                                   const float* __restrict__ beta,
                                                   float* __restrict__ dout) {
    const float* __restrict__ A = (LAYER == 0) ? g_pT : (LAYER == 1) ? g_act1 : g_act2;
    float* __restrict__ O = (LAYER == 0) ? g_act1 : (LAYER == 1) ? g_act2 : dout;
    constexpr int NT = COUT / 16;
    __shared__ ushort_t As[64][36];
    __shared__ ushort_t Bs[COUT][36];
    __shared__ float s_scale[(LAYER >= 1) ? CIN : 1];
    __shared__ float s_shift[(LAYER >= 1) ? CIN : 1];
    __shared__ float s_red[(LAYER < 2) ? 2 : 1][(LAYER < 2) ? 4 : 1][(LAYER < 2) ? COUT : 1];

    const int t = threadIdx.x;
    const int lane = t & 63, w = t >> 6;
    const int q = lane >> 4, nlo = lane & 15;
    const int row0 = blockIdx.x * 64;
    const int arow_i = t >> 2, acg = t & 3;

    if constexpr (LAYER >= 1) {
        const float* sb = (LAYER == 1) ? g_sums : (g_sums + 256);
        if (t < CIN) {
            float mu  = sb[t] * (1.0f / 65536.0f);
            float var = sb[CIN + t] * (1.0f / 65536.0f) - mu * mu;
            var = fmaxf(var, 0.0f);
            float sc = gamma[t] / sqrtf(var + 1e-5f);
            s_scale[t] = sc;
            s_shift[t] = beta[t] - mu * sc;
        }
        __syncthreads();
    }

    size_t arow;
    if (LAYER == 0) {
        const int row = row0 + arow_i;
        const int b = row >> 13;
        const int n = g_knn[row] & (NPTS - 1);
        arow = (size_t)(b * NPTS + n) * 64;
    } else {
        arow = (size_t)(row0 + arow_i) * CIN;
    }
    const float* Sbase = g_S + (size_t)LAYER * NROWS * 8 + (size_t)(row0 + arow_i) * 8;
    const int bn = t & 63, bkg = t >> 6;

    f32x4 acc[NT];
    #pragma unroll
    for (int i = 0; i < NT; ++i) acc[i] = (f32x4){0.f, 0.f, 0.f, 0.f};

    for (int m = 0; m < 8; ++m) {
        const float sv = Sbase[m];
        for (int c0 = 0; c0 < CIN; c0 += 32) {
            // ---- stage A ((BN+relu)?, *S, RNE bf16) ----
            {
                const float* ap = A + arow + c0 + acg * 8;
                float4 fa = *reinterpret_cast<const float4*>(ap);
                float4 fb = *reinterpret_cast<const float4*>(ap + 4);
                float v0 = fa.x, v1 = fa.y, v2 = fa.z, v3 = fa.w;
                float v4 = fb.x, v5 = fb.y, v6 = fb.z, v7 = fb.w;
                if constexpr (LAYER >= 1) {
                    const int c = c0 + acg * 8;
                    v0 = fmaxf(v0 * s_scale[c+0] + s_shift[c+0], 0.f);
                    v1 = fmaxf(v1 * s_scale[c+1] + s_shift[c+1], 0.f);
                    v2 = fmaxf(v2 * s_scale[c+2] + s_shift[c+2], 0.f);
                    v3 = fmaxf(v3 * s_scale[c+3] + s_shift[c+3], 0.f);
                    v4 = fmaxf(v4 * s_scale[c+4] + s_shift[c+4], 0.f);
                    v5 = fmaxf(v5 * s_scale[c+5] + s_shift[c+5], 0.f);
                    v6 = fmaxf(v6 * s_scale[c+6] + s_shift[c+6], 0.f);
                    v7 = fmaxf(v7 * s_scale[c+7] + s_shift[c+7], 0.f);
                }
                uint_t p0 = (uint_t)f2bf(sv*v0) | ((uint_t)f2bf(sv*v1) << 16);
                uint_t p1 = (uint_t)f2bf(sv*v2) | ((uint_t)f2bf(sv*v3) << 16);
                uint_t p2 = (uint_t)f2bf(sv*v4) | ((uint_t)f2bf(sv*v5) << 16);
                uint_t p3 = (uint_t)f2bf(sv*v6) | ((uint_t)f2bf(sv*v7) << 16);
                uint_t* dst = reinterpret_cast<uint_t*>(&As[arow_i][acg * 8]);
                dst[0] = p0; dst[1] = p1; dst[2] = p2; dst[3] = p3;
            }
            // ---- stage B transposed (bank -> bf16) ----
            {
                const int k0 = m * CIN + c0;
                #pragma unroll
                for (int no = 0; no < COUT; no += 64) {
                    const int n = no + bn;
                    #pragma unroll
                    for (int j = 0; j < 8; j += 2) {
                        float v0 = bank[(size_t)(k0 + bkg*8 + j    ) * COUT + n];
                        float v1 = bank[(size_t)(k0 + bkg*8 + j + 1) * COUT + n];
                        uint_t pk = (uint_t)f2bf(v0) | ((uint_t)f2bf(v1) << 16);
                        *reinterpret_cast<uint_t*>(&Bs[n][bkg*8 + j]) = pk;
                    }
                }
            }
            __syncthreads();
            // ---- MFMA ----
            union FragU { uint2 u2[2]; short8 s; } af;
            af.u2[0] = *reinterpret_cast<const uint2*>(&As[w*16 + nlo][q*8]);
            af.u2[1] = *reinterpret_cast<const uint2*>(&As[w*16 + nlo][q*8 + 4]);
            #pragma unroll
            for (int nt = 0; nt < NT; ++nt) {
                FragU bf;
                bf.u2[0] = *reinterpret_cast<const uint2*>(&Bs[nt*16 + nlo][q*8]);
                bf.u2[1] = *reinterpret_cast<const uint2*>(&Bs[nt*16 + nlo][q*8 + 4]);
                acc[nt] = __builtin_amdgcn_mfma_f32_16x16x32_bf16(af.s, bf.s, acc[nt], 0, 0, 0);
            }
            __syncthreads();
        }
    }

    if constexpr (LAYER == 2) {
        // wave w holds rows w*16..w*16+15 = all K=16 neighbors of one (b,p)
        const int bp = (row0 >> 4) + w;
        const int b = bp >> 9, p = bp & 511;
        #pragma unroll
        for (int nt = 0; nt < NT; ++nt) {
            float mv = fmaxf(fmaxf(acc[nt][0], acc[nt][1]), fmaxf(acc[nt][2], acc[nt][3]));
            mv = fmaxf(mv, __shfl_xor(mv, 16));
            mv = fmaxf(mv, __shfl_xor(mv, 32));
            if (lane < 16)
                O[(size_t)(b * 256 + nt*16 + nlo) * NPOINT + p] = mv;
        }
    } else {
        // raw output + fused per-channel sum/sumsq
        #pragma unroll
        for (int nt = 0; nt < NT; ++nt)
            #pragma unroll
            for (int r2 = 0; r2 < 4; ++r2)
                O[(size_t)(row0 + w*16 + q*4 + r2) * COUT + nt*16 + nlo] = acc[nt][r2];
        #pragma unroll
        for (int nt = 0; nt < NT; ++nt) {
            float s  = acc[nt][0] + acc[nt][1] + acc[nt][2] + acc[nt][3];
            float ss = acc[nt][0]*acc[nt][0] + acc[nt][1]*acc[nt][1]
                     + acc[nt][2]*acc[nt][2] + acc[nt][3]*acc[nt][3];
            s  += __shfl_xor(s, 16);  s  += __shfl_xor(s, 32);
            ss += __shfl_xor(ss, 16); ss += __shfl_xor(ss, 32);
            if (q == 0) {
                s_red[0][w][nt*16 + nlo] = s;
                s_red[1][w][nt*16 + nlo] = ss;
            }
        }
        __syncthreads();
        if (t < COUT) {
            float s  = s_red[0][0][t] + s_red[0][1][t] + s_red[0][2][t] + s_red[0][3][t];
            float ss = s_red[1][0][t] + s_red[1][1][t] + s_red[1][2][t] + s_red[1][3][t];
            float* sb = (LAYER == 0) ? g_sums : (g_sums + 256);
            atomicAdd(&sb[t], s);
            atomicAdd(&sb[COUT + t], ss);
        }
    }
}

// ---------------------------------------------------------------------------
extern "C" void kernel_launch(void* const* d_in, const int* in_sizes, int n_in,
                              void* d_out, int out_size, void* d_ws, size_t ws_size,
                              hipStream_t stream) {
    const float* xyz    = (const float*)d_in[0];
    const float* nrm    = (const float*)d_in[1];
    const float* Xa     = (const float*)d_in[2];
    const float* Ya     = (const float*)d_in[3];
    const float* points = (const float*)d_in[4];
    const float* w1_0 = (const float*)d_in[5];  const float* b1_0 = (const float*)d_in[6];
    const float* w2_0 = (const float*)d_in[7];  const float* b2_0 = (const float*)d_in[8];
    const float* bank0 = (const float*)d_in[9];
    const float* g0 = (const float*)d_in[10];   const float* be0 = (const float*)d_in[11];
    const float* w1_1 = (const float*)d_in[12]; const float* b1_1 = (const float*)d_in[13];
    const float* w2_1 = (const float*)d_in[14]; const float* b2_1 = (const float*)d_in[15];
    const float* bank1 = (const float*)d_in[16];
    const float* g1 = (const float*)d_in[17];   const float* be1 = (const float*)d_in[18];
    const float* w1_2 = (const float*)d_in[19]; const float* b1_2 = (const float*)d_in[20];
    const float* w2_2 = (const float*)d_in[21]; const float* b2_2 = (const float*)d_in[22];
    const float* bank2 = (const float*)d_in[23];
    float* out = (float*)d_out;
    (void)d_ws; (void)ws_size; (void)in_sizes; (void)n_in; (void)out_size;

    // fps (blocks 0-7) + transpose (8-263) + zero sums (264)
    front_kernel<<<265, 256, 0, stream>>>(xyz, points);
    knn_kernel<<<1024, 256, 0, stream>>>(xyz);
    // geometry + all 3 score MLPs (blocks 0-255) + small outputs (256-271)
    score3_kernel<<<272, 256, 0, stream>>>(xyz, nrm, Xa, Ya,
                                           w1_0, b1_0, w2_0, b2_0,
                                           w1_1, b1_1, w2_1, b2_1,
                                           w1_2, b1_2, w2_2, b2_2, out);
    // layer 0: gather+GEMM -> raw act1 + BN stats
    gemm_kernel<0, 64, 64><<<1024, 256, 0, stream>>>(bank0, nullptr, nullptr, nullptr);
    // layer 1: BN0+relu fused in staging -> raw act2 + BN stats
    gemm_kernel<1, 64, 128><<<1024, 256, 0, stream>>>(bank1, g0, be0, nullptr);
    // layer 2: BN1+relu fused in staging -> fused max-k + transpose to d_out
    gemm_kernel<2, 128, 256><<<1024, 256, 0, stream>>>(bank2, g1, be1, out + 49152);
}

// Round 10
// 742.458 us; speedup vs baseline: 2.1963x; 1.0959x over previous
//
#include <hip/hip_runtime.h>
#include <math.h>

#define NBATCH 8
#define NPTS   2048
#define NPOINT 512
#define KNB    16
#define NROWS  (NBATCH*NPOINT*KNB)   // 65536

typedef unsigned short ushort_t;
typedef unsigned int   uint_t;
typedef unsigned long long ull_t;
typedef __attribute__((ext_vector_type(8))) short  short8;   // 8 bf16 (4 VGPRs)
typedef __attribute__((ext_vector_type(4))) float  f32x4;    // MFMA C/D

// ---------------------------------------------------------------------------
// Scratch in static __device__ globals. Referenced ONLY in device code.
// ---------------------------------------------------------------------------
__device__ __align__(16) int   g_fidx[NBATCH * NPOINT];           //  16 KB
__device__ __align__(16) int   g_knn [NROWS];                     // 256 KB
__device__ __align__(16) float g_sums[1024];                      //   4 KB
__device__ __align__(16) float g_pT  [NBATCH * NPTS * 64];        //   4 MB
__device__ __align__(16) float g_S   [(size_t)3 * NROWS * 8];     //   6 MB (3 layers)
__device__ __align__(16) float g_act1[(size_t)NROWS * 64];        //  16 MB (raw gemm0 out)
__device__ __align__(16) float g_act2[(size_t)NROWS * 128];       //  32 MB (raw gemm1 out)

// f32 -> bf16 round-to-nearest-even (finite inputs).
__device__ __forceinline__ ushort_t f2bf(float f) {
    uint_t u = __float_as_uint(f);
    return (ushort_t)((u + 0x7FFFu + ((u >> 16) & 1u)) >> 16);
}

// DPP-shifted copy of a u64 key (bound_ctrl=1: invalid lanes read 0, the
// identity for unsigned max of our non-negative keys).
template<int CTRL>
__device__ __forceinline__ ull_t dpp_u64(ull_t k) {
    int lo = (int)(uint_t)k;
    int hi = (int)(uint_t)(k >> 32);
    int slo = __builtin_amdgcn_update_dpp(0, lo, CTRL, 0xF, 0xF, true);
    int shi = __builtin_amdgcn_update_dpp(0, hi, CTRL, 0xF, 0xF, true);
    return ((ull_t)(uint_t)shi << 32) | (uint_t)slo;
}

// ---------------------------------------------------------------------------
// front_kernel: blocks 0-7 = FPS (one block per batch), 8-263 = transpose
// points [b][c][n]->[b][n][c], 264 = zero g_sums.
// FPS: 4 waves, 8 pts/lane in regs, coords mirrored in LDS. Argmax key =
// (f32bits(dist)<<32)|~idx (dist>=0 -> monotone bits; ties -> smaller idx =
// numpy argmax). Wave reduce via DPP (row_shr 1/2/4/8 + row_bcast 15/31 ->
// wave max in lane 63, VALU latency — replaces the ds_bpermute butterfly),
// then readlane(63). Cross-wave via parity-double-buffered s_key + ONE
// barrier per iteration (write slot i&1 pre-barrier, read post-barrier).
// ---------------------------------------------------------------------------
__global__ __launch_bounds__(256) void front_kernel(const float* __restrict__ xyz,
                                                    const float* __restrict__ points) {
    __shared__ float smem[3 * NPTS + 16];
    const int bid = blockIdx.x;
    const int t = threadIdx.x;

    if (bid >= NBATCH) {
        if (bid < NBATCH + 256) {
            // ---- transpose ----
            float (*tile)[65] = reinterpret_cast<float(*)[65]>(smem);
            const int blk = bid - NBATCH;
            const int b = blk >> 5;
            const int n0 = (blk & 31) * 64;
            const int lane = t & 63, q = t >> 6;
            #pragma unroll
            for (int i = 0; i < 16; ++i) {
                int c = q * 16 + i;
                tile[c][lane] = points[(b * 64 + c) * NPTS + n0 + lane];
            }
            __syncthreads();
            #pragma unroll
            for (int i = 0; i < 16; ++i) {
                int n = q * 16 + i;
                g_pT[(size_t)(b * NPTS + n0 + n) * 64 + lane] = tile[lane][n];
            }
        } else {
            // ---- zero BN-stats (must run every call: atomics accumulate) ----
            #pragma unroll
            for (int j = 0; j < 4; ++j) g_sums[j * 256 + t] = 0.0f;
        }
        return;
    }

    // ---- FPS ----
    {
        #pragma clang fp contract(off)
        const int b = bid;
        const int lane = t & 63, w4 = t >> 6;
        const float* xb = xyz + b * 3 * NPTS;
        float* s_x = smem;
        float* s_y = smem + NPTS;
        float* s_z = smem + 2 * NPTS;
        ull_t* s_key = reinterpret_cast<ull_t*>(smem + 3 * NPTS);  // 8 slots
        float x[8], y[8], z[8], d[8];
        #pragma unroll
        for (int j = 0; j < 8; ++j) {
            int p = j * 256 + t;
            float vx = xb[p], vy = xb[NPTS + p], vz = xb[2*NPTS + p];
            x[j] = vx; y[j] = vy; z[j] = vz;
            s_x[p] = vx; s_y[p] = vy; s_z[p] = vz;
            d[j] = 1e10f;
        }
        __syncthreads();
        int far = 0;
        for (int i = 0; i < NPOINT; ++i) {
            if (t == 0) g_fidx[b * NPOINT + i] = far;
            float cx = s_x[far], cy = s_y[far], cz = s_z[far];
            float best = -1.0f; int bi = 0;
            #pragma unroll
            for (int j = 0; j < 8; ++j) {
                float dx = x[j] - cx;
                float dy = y[j] - cy;
                float dz = z[j] - cz;
                float dd = dx*dx + dy*dy;   // ((dx^2+dy^2)+dz^2) like np
                dd = dd + dz*dz;
                float dn = fminf(d[j], dd);
                d[j] = dn;
                if (dn > best) { best = dn; bi = j * 256 + t; }  // strict >
            }
            ull_t key = (((ull_t)__float_as_uint(best)) << 32) | (uint_t)(~bi);
            // DPP wave max -> lane 63
            { ull_t s = dpp_u64<0x111>(key); if (s > key) key = s; }  // row_shr:1
            { ull_t s = dpp_u64<0x112>(key); if (s > key) key = s; }  // row_shr:2
            { ull_t s = dpp_u64<0x114>(key); if (s > key) key = s; }  // row_shr:4
            { ull_t s = dpp_u64<0x118>(key); if (s > key) key = s; }  // row_shr:8
            { ull_t s = dpp_u64<0x142>(key); if (s > key) key = s; }  // row_bcast:15
            { ull_t s = dpp_u64<0x143>(key); if (s > key) key = s; }  // row_bcast:31
            uint_t wlo = (uint_t)__builtin_amdgcn_readlane((int)(uint_t)key, 63);
            uint_t whi = (uint_t)__builtin_amdgcn_readlane((int)(uint_t)(key >> 32), 63);
            if (lane == 0) s_key[((i & 1) << 2) + w4] = ((ull_t)whi << 32) | wlo;
            __syncthreads();
            const ull_t* kb = s_key + ((i & 1) << 2);
            ull_t k0 = kb[0], k1 = kb[1], k2 = kb[2], k3 = kb[3];
            if (k1 > k0) k0 = k1;
            if (k3 > k2) k2 = k3;
            if (k2 > k0) k0 = k2;
            far = (int)(~(uint_t)k0) & (NPTS - 1);
        }
    }
}

// ---------------------------------------------------------------------------
// KNN: one wave per query. Expanded |a|^2+|b|^2-2ab form (contract off);
// 16 rounds of wave-min with index tie-break.
// ---------------------------------------------------------------------------
__global__ __launch_bounds__(256) void knn_kernel(const float* __restrict__ xyz) {
    #pragma clang fp contract(off)
    const int wave = blockIdx.x * 4 + (threadIdx.x >> 6);
    const int lane = threadIdx.x & 63;
    const int b = wave >> 9;
    const float* xb = xyz + b * 3 * NPTS;
    const int fi = g_fidx[wave] & (NPTS - 1);
    float ax = xb[fi];
    float ay = xb[NPTS + fi];
    float az = xb[2*NPTS + fi];
    float sa = ax*ax + ay*ay; sa = sa + az*az;
    float d[32];
    #pragma unroll
    for (int j = 0; j < 32; ++j) {
        int p = j * 64 + lane;
        float bx = xb[p];
        float by = xb[NPTS + p];
        float bz = xb[2*NPTS + p];
        float sb = bx*bx + by*by; sb = sb + bz*bz;
        float dot = ax*bx + ay*by; dot = dot + az*bz;
        float t1 = sa + sb;
        float t2 = 2.0f * dot;
        d[j] = t1 - t2;
    }
    for (int r = 0; r < KNB; ++r) {
        float best = 1e30f; int bi = 0x7fffffff;
        #pragma unroll
        for (int j = 0; j < 32; ++j) {
            if (d[j] < best) { best = d[j]; bi = j * 64 + lane; }
        }
        #pragma unroll
        for (int m = 32; m >= 1; m >>= 1) {
            float ov = __shfl_xor(best, m);
            int   oi = __shfl_xor(bi, m);
            if (ov < best || (ov == best && oi < bi)) { best = ov; bi = oi; }
        }
        bi &= (NPTS - 1);
        if (lane == 0) g_knn[wave * KNB + r] = bi;
        int rl = bi & 63, rs = bi >> 6;
        if (lane == rl) {
            #pragma unroll
            for (int j = 0; j < 32; ++j) if (j == rs) d[j] = 1e30f;
        }
    }
}

// ---------------------------------------------------------------------------
// score3_kernel: blocks 0-255 compute geometry ONCE and all THREE scoring
// MLPs (S0,S1,S2); blocks 256-271 do the small gathered outputs.
// ---------------------------------------------------------------------------
__global__ __launch_bounds__(256) void score3_kernel(
    const float* __restrict__ xyz, const float* __restrict__ nrm,
    const float* __restrict__ Xa, const float* __restrict__ Ya,
    const float* __restrict__ w1_0, const float* __restrict__ b1_0,
    const float* __restrict__ w2_0, const float* __restrict__ b2_0,
    const float* __restrict__ w1_1, const float* __restrict__ b1_1,
    const float* __restrict__ w2_1, const float* __restrict__ b2_1,
    const float* __restrict__ w1_2, const float* __restrict__ b1_2,
    const float* __restrict__ w2_2, const float* __restrict__ b2_2,
    float* __restrict__ out) {
    const int bid = blockIdx.x;
    const int t = threadIdx.x;
    if (bid >= 256) {
        // ---- small outputs: new_xyz (fidx), new_norm/X/Y (knn[...,0]) ----
        const int g = (bid - 256) * 256 + t;       // b*512+p
        const int b = g / NPOINT, p = g % NPOINT;
        const int fi = g_fidx[g] & (NPTS - 1);
        const int n0 = g_knn[g * KNB] & (NPTS - 1);
        #pragma unroll
        for (int a = 0; a < 3; ++a) {
            out[            (b*3 + a) * NPOINT + p] = xyz[(b*3 + a) * NPTS + fi];
            out[12288 +     (b*3 + a) * NPOINT + p] = nrm[(b*3 + a) * NPTS + n0];
            out[24576 +     (b*3 + a) * NPOINT + p] = Xa [(b*3 + a) * NPTS + n0];
            out[36864 +     (b*3 + a) * NPOINT + p] = Ya [(b*3 + a) * NPTS + n0];
        }
        return;
    }
    __shared__ float w1s[3][16][10];
    __shared__ float b1s[3][16];
    __shared__ float w2s[3][8][16];
    __shared__ float b2s[3][8];
    {
        const float* w1p[3] = {w1_0, w1_1, w1_2};
        const float* b1p[3] = {b1_0, b1_1, b1_2};
        const float* w2p[3] = {w2_0, w2_1, w2_2};
        const float* b2p[3] = {b2_0, b2_1, b2_2};
        #pragma unroll
        for (int l = 0; l < 3; ++l) {
            if (t < 160) w1s[l][t / 10][t % 10] = w1p[l][t];
            if (t < 16)  b1s[l][t] = b1p[l][t];
            if (t < 128) w2s[l][t / 16][t % 16] = w2p[l][t];
            if (t < 8)   b2s[l][t] = b2p[l][t];
        }
    }
    __syncthreads();
    const int row = bid * 256 + t;
    const int b = row >> 13;
    const int p = (row >> 4) & 511;
    const int n = g_knn[row] & (NPTS - 1);
    const int fi = g_fidx[b * NPOINT + p] & (NPTS - 1);
    const float* xb = xyz + b * 3 * NPTS;
    const float* nb = nrm + b * 3 * NPTS;
    const float* Xb = Xa  + b * 3 * NPTS;
    const float* Yb = Ya  + b * 3 * NPTS;
    float gx, gy, gz, sq, draw, nnv;
    {
        #pragma clang fp contract(off)
        gx = xb[n]        - xb[fi];
        gy = xb[NPTS + n] - xb[NPTS + fi];
        gz = xb[2*NPTS+n] - xb[2*NPTS+fi];
        sq = gx*gx + gy*gy;
        sq = sq + gz*gz;
        draw = sqrtf(sq + 1e-10f);
        nnv = sqrtf(sq);
    }
    float dmin = draw, dmax = draw;
    #pragma unroll
    for (int m = 1; m < 16; m <<= 1) {
        dmin = fminf(dmin, __shfl_xor(dmin, m, 16));
        dmax = fmaxf(dmax, __shfl_xor(dmax, m, 16));
    }
    float dist;
    {
        #pragma clang fp contract(off)
        dist = (draw - dmin) / ((dmax - dmin) + 1e-10f);
    }
    float nx = nb[n], ny = nb[NPTS+n], nz = nb[2*NPTS+n];
    float Xx = Xb[n], Xy = Xb[NPTS+n], Xz = Xb[2*NPTS+n];
    float Yx = Yb[n], Yy = Yb[NPTS+n], Yz = Yb[2*NPTS+n];
    float g[10];
    g[0]=gx; g[1]=gy; g[2]=gz; g[3]=dist; g[4]=nx; g[5]=ny; g[6]=nz;
    {
        float vs[3][3] = {{nx,ny,nz},{Xx,Xy,Xz},{Yx,Yy,Yz}};
        #pragma unroll
        for (int a = 0; a < 3; ++a) {
            float vx=vs[a][0], vy=vs[a][1], vz=vs[a][2];
            float dot, nv;
            {
                #pragma clang fp contract(off)
                dot = gx*vx + gy*vy; dot = dot + gz*vz;
                float s2 = vx*vx + vy*vy; s2 = s2 + vz*vz;
                nv = sqrtf(s2);
            }
            float cc = dot / (nnv * nv + 1e-8f);
            cc = fminf(1.0f, fmaxf(-1.0f, cc));
            g[7+a] = acosf(cc) / 3.14159274101257324f;
        }
    }
    #pragma unroll
    for (int l = 0; l < 3; ++l) {
        float h[16];
        #pragma unroll
        for (int i = 0; i < 16; ++i) {
            float a = b1s[l][i];
            #pragma unroll
            for (int j = 0; j < 10; ++j) a += w1s[l][i][j] * g[j];
            h[i] = fmaxf(a, 0.0f);
        }
        float e[8]; float mx = -1e30f;
        #pragma unroll
        for (int m = 0; m < 8; ++m) {
            float a = b2s[l][m];
            #pragma unroll
            for (int j = 0; j < 16; ++j) a += w2s[l][m][j] * h[j];
            e[m] = a; mx = fmaxf(mx, a);
        }
        float sum = 0.0f;
        #pragma unroll
        for (int m = 0; m < 8; ++m) { e[m] = expf(e[m] - mx); sum += e[m]; }
        #pragma unroll
        for (int m = 0; m < 8; ++m)
            g_S[(size_t)l * NROWS * 8 + (size_t)row * 8 + m] = e[m] / sum;
    }
}

// ---------------------------------------------------------------------------
// MFMA PAConv GEMM, fused BN, K-loop reordered (c0 outer, m inner):
// the A-row global load + BN+relu happen ONCE per c-chunk (cached in regs),
// cutting A global traffic and BN math 8x vs m-outer.
//  - LAYER>=1 staging applies previous layer's BN+relu on the fly.
//  - LAYER<2 epilogue accumulates per-channel sum/sumsq into g_sums.
// ---------------------------------------------------------------------------
template<int LAYER, int CIN, int COUT>
__global__ __launch_bounds__(256) void gemm_kernel(const float* __restrict__ bank,
                                                   const float* __restrict__ gamma,
                                                   const float* __restrict__ beta,
                                                   float* __restrict__ dout) {
    const float* __restrict__ A = (LAYER == 0) ? g_pT : (LAYER == 1) ? g_act1 : g_act2;
    float* __restrict__ O = (LAYER == 0) ? g_act1 : (LAYER == 1) ? g_act2 : dout;
    constexpr int NT = COUT / 16;
    __shared__ ushort_t As[64][36];
    __shared__ ushort_t Bs[COUT][36];
    __shared__ float s_scale[(LAYER >= 1) ? CIN : 1];
    __shared__ float s_shift[(LAYER >= 1) ? CIN : 1];
    __shared__ float s_red[(LAYER < 2) ? 2 : 1][(LAYER < 2) ? 4 : 1][(LAYER < 2) ? COUT : 1];

    const int t = threadIdx.x;
    const int lane = t & 63, w = t >> 6;
    const int q = lane >> 4, nlo = lane & 15;
    const int row0 = blockIdx.x * 64;
    const int arow_i = t >> 2, acg = t & 3;

    if constexpr (LAYER >= 1) {
        const float* sb = (LAYER == 1) ? g_sums : (g_sums + 256);
        if (t < CIN) {
            float mu  = sb[t] * (1.0f / 65536.0f);
            float var = sb[CIN + t] * (1.0f / 65536.0f) - mu * mu;
            var = fmaxf(var, 0.0f);
            float sc = gamma[t] / sqrtf(var + 1e-5f);
            s_scale[t] = sc;
            s_shift[t] = beta[t] - mu * sc;
        }
        __syncthreads();
    }

    size_t arow;
    if (LAYER == 0) {
        const int row = row0 + arow_i;
        const int b = row >> 13;
        const int n = g_knn[row] & (NPTS - 1);
        arow = (size_t)(b * NPTS + n) * 64;
    } else {
        arow = (size_t)(row0 + arow_i) * CIN;
    }
    const float* Sbase = g_S + (size_t)LAYER * NROWS * 8 + (size_t)(row0 + arow_i) * 8;
    const int bn = t & 63, bkg = t >> 6;

    float svv[8];
    #pragma unroll
    for (int m = 0; m < 8; ++m) svv[m] = Sbase[m];

    f32x4 acc[NT];
    #pragma unroll
    for (int i = 0; i < NT; ++i) acc[i] = (f32x4){0.f, 0.f, 0.f, 0.f};

    for (int c0 = 0; c0 < CIN; c0 += 32) {
        // ---- load F chunk once, apply BN+relu once ----
        float v[8];
        {
            const float* ap = A + arow + c0 + acg * 8;
            float4 fa = *reinterpret_cast<const float4*>(ap);
            float4 fb = *reinterpret_cast<const float4*>(ap + 4);
            v[0]=fa.x; v[1]=fa.y; v[2]=fa.z; v[3]=fa.w;
            v[4]=fb.x; v[5]=fb.y; v[6]=fb.z; v[7]=fb.w;
            if constexpr (LAYER >= 1) {
                const int c = c0 + acg * 8;
                #pragma unroll
                for (int j = 0; j < 8; ++j)
                    v[j] = fmaxf(v[j] * s_scale[c + j] + s_shift[c + j], 0.f);
            }
        }
        for (int m = 0; m < 8; ++m) {
            // ---- stage A (sv[m]*F -> bf16) ----
            {
                const float sv = svv[m];
                uint_t* dst = reinterpret_cast<uint_t*>(&As[arow_i][acg * 8]);
                #pragma unroll
                for (int j = 0; j < 8; j += 2)
                    dst[j >> 1] = (uint_t)f2bf(sv * v[j]) | ((uint_t)f2bf(sv * v[j+1]) << 16);
            }
            // ---- stage B transposed (bank -> bf16) ----
            {
                const int k0 = m * CIN + c0;
                #pragma unroll
                for (int no = 0; no < COUT; no += 64) {
                    const int n = no + bn;
                    #pragma unroll
                    for (int j = 0; j < 8; j += 2) {
                        float b0 = bank[(size_t)(k0 + bkg*8 + j    ) * COUT + n];
                        float b1 = bank[(size_t)(k0 + bkg*8 + j + 1) * COUT + n];
                        *reinterpret_cast<uint_t*>(&Bs[n][bkg*8 + j]) =
                            (uint_t)f2bf(b0) | ((uint_t)f2bf(b1) << 16);
                    }
                }
            }
            __syncthreads();
            // ---- MFMA ----
            union FragU { uint2 u2[2]; short8 s; } af;
            af.u2[0] = *reinterpret_cast<const uint2*>(&As[w*16 + nlo][q*8]);
            af.u2[1] = *reinterpret_cast<const uint2*>(&As[w*16 + nlo][q*8 + 4]);
            #pragma unroll
            for (int nt = 0; nt < NT; ++nt) {
                FragU bf;
                bf.u2[0] = *reinterpret_cast<const uint2*>(&Bs[nt*16 + nlo][q*8]);
                bf.u2[1] = *reinterpret_cast<const uint2*>(&Bs[nt*16 + nlo][q*8 + 4]);
                acc[nt] = __builtin_amdgcn_mfma_f32_16x16x32_bf16(af.s, bf.s, acc[nt], 0, 0, 0);
            }
            __syncthreads();
        }
    }

    if constexpr (LAYER == 2) {
        // wave w holds rows w*16..w*16+15 = all K=16 neighbors of one (b,p)
        const int bp = (row0 >> 4) + w;
        const int b = bp >> 9, p = bp & 511;
        #pragma unroll
        for (int nt = 0; nt < NT; ++nt) {
            float mv = fmaxf(fmaxf(acc[nt][0], acc[nt][1]), fmaxf(acc[nt][2], acc[nt][3]));
            mv = fmaxf(mv, __shfl_xor(mv, 16));
            mv = fmaxf(mv, __shfl_xor(mv, 32));
            if (lane < 16)
                O[(size_t)(b * 256 + nt*16 + nlo) * NPOINT + p] = mv;
        }
    } else {
        // raw output + fused per-channel sum/sumsq
        #pragma unroll
        for (int nt = 0; nt < NT; ++nt)
            #pragma unroll
            for (int r2 = 0; r2 < 4; ++r2)
                O[(size_t)(row0 + w*16 + q*4 + r2) * COUT + nt*16 + nlo] = acc[nt][r2];
        #pragma unroll
        for (int nt = 0; nt < NT; ++nt) {
            float s  = acc[nt][0] + acc[nt][1] + acc[nt][2] + acc[nt][3];
            float ss = acc[nt][0]*acc[nt][0] + acc[nt][1]*acc[nt][1]
                     + acc[nt][2]*acc[nt][2] + acc[nt][3]*acc[nt][3];
            s  += __shfl_xor(s, 16);  s  += __shfl_xor(s, 32);
            ss += __shfl_xor(ss, 16); ss += __shfl_xor(ss, 32);
            if (q == 0) {
                s_red[0][w][nt*16 + nlo] = s;
                s_red[1][w][nt*16 + nlo] = ss;
            }
        }
        __syncthreads();
        if (t < COUT) {
            float s  = s_red[0][0][t] + s_red[0][1][t] + s_red[0][2][t] + s_red[0][3][t];
            float ss = s_red[1][0][t] + s_red[1][1][t] + s_red[1][2][t] + s_red[1][3][t];
            float* sb = (LAYER == 0) ? g_sums : (g_sums + 256);
            atomicAdd(&sb[t], s);
            atomicAdd(&sb[COUT + t], ss);
        }
    }
}

// ---------------------------------------------------------------------------
extern "C" void kernel_launch(void* const* d_in, const int* in_sizes, int n_in,
                              void* d_out, int out_size, void* d_ws, size_t ws_size,
                              hipStream_t stream) {
    const float* xyz    = (const float*)d_in[0];
    const float* nrm    = (const float*)d_in[1];
    const float* Xa     = (const float*)d_in[2];
    const float* Ya     = (const float*)d_in[3];
    const float* points = (const float*)d_in[4];
    const float* w1_0 = (const float*)d_in[5];  const float* b1_0 = (const float*)d_in[6];
    const float* w2_0 = (const float*)d_in[7];  const float* b2_0 = (const float*)d_in[8];
    const float* bank0 = (const float*)d_in[9];
    const float* g0 = (const float*)d_in[10];   const float* be0 = (const float*)d_in[11];
    const float* w1_1 = (const float*)d_in[12]; const float* b1_1 = (const float*)d_in[13];
    const float* w2_1 = (const float*)d_in[14]; const float* b2_1 = (const float*)d_in[15];
    const float* bank1 = (const float*)d_in[16];
    const float* g1 = (const float*)d_in[17];   const float* be1 = (const float*)d_in[18];
    const float* w1_2 = (const float*)d_in[19]; const float* b1_2 = (const float*)d_in[20];
    const float* w2_2 = (const float*)d_in[21]; const float* b2_2 = (const float*)d_in[22];
    const float* bank2 = (const float*)d_in[23];
    float* out = (float*)d_out;
    (void)d_ws; (void)ws_size; (void)in_sizes; (void)n_in; (void)out_size;

    // fps (blocks 0-7) + transpose (8-263) + zero sums (264)
    front_kernel<<<265, 256, 0, stream>>>(xyz, points);
    knn_kernel<<<1024, 256, 0, stream>>>(xyz);
    // geometry + all 3 score MLPs (blocks 0-255) + small outputs (256-271)
    score3_kernel<<<272, 256, 0, stream>>>(xyz, nrm, Xa, Ya,
                                           w1_0, b1_0, w2_0, b2_0,
                                           w1_1, b1_1, w2_1, b2_1,
                                           w1_2, b1_2, w2_2, b2_2, out);
    // layer 0: gather+GEMM -> raw act1 + BN stats
    gemm_kernel<0, 64, 64><<<1024, 256, 0, stream>>>(bank0, nullptr, nullptr, nullptr);
    // layer 1: BN0+relu fused in staging -> raw act2 + BN stats
    gemm_kernel<1, 64, 128><<<1024, 256, 0, stream>>>(bank1, g0, be0, nullptr);
    // layer 2: BN1+relu fused in staging -> fused max-k + transpose to d_out
    gemm_kernel<2, 128, 256><<<1024, 256, 0, stream>>>(bank2, g1, be1, out + 49152);
}